// Round 8
// baseline (543.341 us; speedup 1.0000x reference)
//
#include <hip/hip_runtime.h>

// ReadInAttention — v7: v3's 8-stage pipeline with 4 blocks/CU occupancy.
// v3's verified gcore8 (2-way K-split x 2-way row-split, dual 8-deep B
// prefetch, LDS kred). Changes vs v3:
//  - __launch_bounds__(256, 4) on all stages: 4 blocks/CU = 4 waves/SIMD
//    (was 2). v2's lone counter row showed VALUBusy 11.8% at 2 blocks/CU
//    -> stages are latency-bound; double the latency-hiding TLP.
//  - s3/s5/s7/s8 multi-partial staging reads float4-vectorized (numerics
//    verified in v5/v6 runs).
//  - v6's atomic epilogue reverted (196.0 vs v3's 186.9 -> dead lever).

#define DD 768
#define CDIM 384
#define NH 8
#define HD 64
#define INNER 512
#define VV 256

__device__ __forceinline__ float4 ldf4(const float* p) {
  return *(const float4*)(p);
}

__device__ __forceinline__ void fma4(float4& a, float s, const float4& b) {
  a.x += s * b.x; a.y += s * b.y; a.z += s * b.z; a.w += s * b.w;
}

// 8 rows x 8 k FMA block. A fragments as float4 pairs (2 rows at a time).
__device__ __forceinline__ void fma_chunk8(const float* __restrict__ Aw,
                                           int lda, int kk, const float4* b,
                                           float4* acc) {
#pragma unroll
  for (int rg = 0; rg < 4; rg++) {
    const float* ap = Aw + (rg * 2) * lda + kk;
    float4 a0l = ldf4(ap);
    float4 a0h = ldf4(ap + 4);
    float4 a1l = ldf4(ap + lda);
    float4 a1h = ldf4(ap + lda + 4);
    float4* ac = acc + rg * 2;
    fma4(ac[0], a0l.x, b[0]); fma4(ac[1], a1l.x, b[0]);
    fma4(ac[0], a0l.y, b[1]); fma4(ac[1], a1l.y, b[1]);
    fma4(ac[0], a0l.z, b[2]); fma4(ac[1], a1l.z, b[2]);
    fma4(ac[0], a0l.w, b[3]); fma4(ac[1], a1l.w, b[3]);
    fma4(ac[0], a0h.x, b[4]); fma4(ac[1], a1h.x, b[4]);
    fma4(ac[0], a0h.y, b[5]); fma4(ac[1], a1h.y, b[5]);
    fma4(ac[0], a0h.z, b[6]); fma4(ac[1], a1h.z, b[6]);
    fma4(ac[0], a0h.w, b[7]); fma4(ac[1], a1h.w, b[7]);
  }
}

// Per-wave GEMM over a K-half: 8 rows x (64 lanes * float4) cols.
// KQ = K/2, multiple of 16. Aw/Bp pre-offset to this wave's rows/K-half.
template <int KQ, int NS>
__device__ __forceinline__ void gcore8(const float* __restrict__ Aw, int lda,
                                       const float* __restrict__ Bp,
                                       float4* acc) {
  float4 b0[8], b1[8];
  const float* Bq = Bp;
#pragma unroll
  for (int i = 0; i < 8; i++) b0[i] = ldf4(Bq + (size_t)i * NS);
  Bq += (size_t)8 * NS;
#pragma unroll 1
  for (int kk = 0; kk + 16 <= KQ; kk += 16) {
#pragma unroll
    for (int i = 0; i < 8; i++) b1[i] = ldf4(Bq + (size_t)i * NS);
    Bq += (size_t)8 * NS;
    fma_chunk8(Aw, lda, kk, b0, acc);
    if (kk + 16 < KQ) {
#pragma unroll
      for (int i = 0; i < 8; i++) b0[i] = ldf4(Bq + (size_t)i * NS);
      Bq += (size_t)8 * NS;
    }
    fma_chunk8(Aw, lda, kk + 8, b1, acc);
  }
}

// Cross-K-half reduce via LDS. After: wave 0 holds rows 0-7, wave 1 rows
// 8-15 (kh==0); waves 2,3 done.
__device__ __forceinline__ void kred(float4* acc, float* RED, int wid,
                                     int kl) {
  __syncthreads();
  float4* R4 = (float4*)RED;
  int rg = wid & 1, kh = wid >> 1;
  if (kh) {
#pragma unroll
    for (int r = 0; r < 8; r++) R4[(rg * 8 + r) * 64 + kl] = acc[r];
  }
  __syncthreads();
  if (!kh) {
#pragma unroll
    for (int r = 0; r < 8; r++) {
      float4 v = R4[(rg * 8 + r) * 64 + kl];
      acc[r].x += v.x; acc[r].y += v.y; acc[r].z += v.z; acc[r].w += v.w;
    }
  }
}

// ===== Stage 1: code GEMM [0,176) | WkT [176,272) | LN [272,1552) ==========
__global__ __launch_bounds__(256, 4) void k_s1(
    const float* __restrict__ ss, const float* __restrict__ rs,
    const float* __restrict__ g_s, const float* __restrict__ b_s,
    const float* __restrict__ g_r, const float* __restrict__ b_r,
    const float* __restrict__ codes, const float* __restrict__ Wmq,
    const float* __restrict__ Wmk, const float* __restrict__ Wmv,
    const float* __restrict__ Wme, const float* __restrict__ Wk,
    float* __restrict__ s_ln, float* __restrict__ r_ln,
    float* __restrict__ cp, float* __restrict__ WkT) {
  __shared__ __align__(16) float SB[6144];
  int bid = blockIdx.x, t = threadIdx.x;
  if (bid < 176) {  // ---- code GEMM: 16 rows x 256 cols, K=384 (192/half) --
    int nc = bid % 11, mb = bid / 11;
    int base = nc * 256;
    const float* W; int N, colW;
    if (base < 768)       { W = Wmq; N = DD;    colW = base; }
    else if (base < 1536) { W = Wmk; N = DD;    colW = base - 768; }
    else if (base < 2304) { W = Wmv; N = DD;    colW = base - 1536; }
    else                  { W = Wme; N = INNER; colW = base - 2304; }
    int m0 = mb * 16;
#pragma unroll
    for (int p = 0; p < 24; p++) {
      int idx = p * 256 + t, r = idx / 384, k = idx % 384;
      SB[idx] = codes[(size_t)(m0 + r) * CDIM + k];
    }
    __syncthreads();
    int kl = t & 63, wid = t >> 6, rg = wid & 1, kh = wid >> 1;
    float4 acc[8] = {};
    const float* Aw = SB + (rg * 8) * 384 + kh * 192;
    if (N == DD)
      gcore8<192, DD>(Aw, 384, W + (size_t)(kh * 192) * DD + colW + 4 * kl, acc);
    else
      gcore8<192, INNER>(Aw, 384, W + (size_t)(kh * 192) * INNER + colW + 4 * kl, acc);
    kred(acc, SB, wid, kl);
    if (!kh) {
      int gcol = base + 4 * kl;
#pragma unroll
      for (int j = 0; j < 8; j++)
        *(float4*)(cp + (size_t)(m0 + rg * 8 + j) * 2816 + gcol) = acc[j];
    }
  } else if (bid < 272) {  // ---- Wk transpose ----
    int tid = bid - 176;
    int d0 = (tid >> 3) * 64, c0 = (tid & 7) * 64;
    int j = t & 63, i0 = t >> 6;
#pragma unroll
    for (int p = 0; p < 16; p++) {
      int i = p * 4 + i0;
      SB[i * 65 + j] = Wk[(size_t)(d0 + i) * INNER + c0 + j];
    }
    __syncthreads();
#pragma unroll
    for (int p = 0; p < 16; p++) {
      int i = p * 4 + i0;
      WkT[(size_t)(c0 + i) * DD + d0 + j] = SB[j * 65 + i];
    }
  } else {  // ---- LayerNorm ----
    int rr = bid - 272;
    const float *x, *g, *bb; float* y; int r;
    if (rr < 1024) { x = ss; g = g_s; bb = b_s; y = s_ln; r = rr; }
    else           { x = rs; g = g_r; bb = b_r; y = r_ln; r = rr - 1024; }
    const float* xr = x + (size_t)r * DD;
    float v0 = xr[t], v1 = xr[t + 256], v2 = xr[t + 512];
    float s = v0 + v1 + v2, sq = v0 * v0 + v1 * v1 + v2 * v2;
    for (int o = 32; o > 0; o >>= 1) {
      s += __shfl_down(s, o, 64); sq += __shfl_down(sq, o, 64);
    }
    int wid = t >> 6, lane = t & 63;
    if (lane == 0) { SB[wid] = s; SB[wid + 4] = sq; }
    __syncthreads();
    float sum = SB[0] + SB[1] + SB[2] + SB[3];
    float ssq = SB[4] + SB[5] + SB[6] + SB[7];
    float mu = sum * (1.0f / 768.0f);
    float var = ssq * (1.0f / 768.0f) - mu * mu;
    float rstd = rsqrtf(var + 1e-5f);
    float* yr = y + (size_t)r * DD;
    yr[t]       = (v0 - mu) * rstd * g[t]       + bb[t];
    yr[t + 256] = (v1 - mu) * rstd * g[t + 256] + bb[t + 256];
    yr[t + 512] = (v2 - mu) * rstd * g[t + 512] + bb[t + 512];
  }
}

// ===== Stage 2: q partial [0,128) (Kc=192, 96/half) | sT [128,320) =========
__global__ __launch_bounds__(256, 4) void k_s2(
    const float* __restrict__ s_ln, const float* __restrict__ r_ln,
    const float* __restrict__ cp, const float* __restrict__ Wq,
    float* __restrict__ sT, float* __restrict__ qp) {
  __shared__ __align__(16) float SB[4160];
  int bid = blockIdx.x, t = threadIdx.x;
  if (bid < 128) {
    int ks = bid & 3, tile = bid >> 2, nc = tile & 1, mb = tile >> 1;
    int m0 = mb * 16, col0 = nc * 256, k0 = ks * 192;
#pragma unroll
    for (int p = 0; p < 12; p++) {
      int idx = p * 256 + t, r = idx / 192, k = idx % 192;
      int d = k0 + k;
      float mqv = cp[(size_t)(m0 + r) * 2816 + d] + 1.0f;
      SB[idx] = r_ln[(size_t)(m0 + r) * DD + d] * mqv;
    }
    __syncthreads();
    int kl = t & 63, wid = t >> 6, rg = wid & 1, kh = wid >> 1;
    int col = col0 + 4 * kl;
    float4 acc[8] = {};
    gcore8<96, INNER>(SB + (rg * 8) * 192 + kh * 96, 192,
                      Wq + (size_t)(k0 + kh * 96) * INNER + col, acc);
    kred(acc, SB, wid, kl);
    if (!kh) {
      float* dst = qp + (size_t)ks * (256 * INNER);
#pragma unroll
      for (int j = 0; j < 8; j++)
        *(float4*)(dst + (size_t)(m0 + rg * 8 + j) * INNER + col) = acc[j];
    }
  } else {  // ---- sT[b][d][v] ----
    int tid = bid - 128;
    int vt = tid & 3, dt = (tid >> 2) % 12, b = tid / 48;
    int v0 = vt * 64, d0 = dt * 64;
    int j = t & 63, i0 = t >> 6;
#pragma unroll
    for (int p = 0; p < 16; p++) {
      int i = p * 4 + i0;
      SB[i * 65 + j] = s_ln[(size_t)(b * VV + v0 + i) * DD + d0 + j];
    }
    __syncthreads();
#pragma unroll
    for (int p = 0; p < 16; p++) {
      int i = p * 4 + i0;
      sT[((size_t)b * DD + d0 + i) * VV + v0 + j] = SB[j * 65 + i];
    }
  }
}

// ===== Stage 3: qmk [0,384) (K=64, 32/half) | qbk [384,640) ================
__global__ __launch_bounds__(256, 4) void k_s3(
    const float* __restrict__ qp, const float* __restrict__ bq,
    const float* __restrict__ WkT, const float* __restrict__ cp,
    const float* __restrict__ bk, float* __restrict__ qm,
    float* __restrict__ qbk) {
  __shared__ __align__(16) float SB[4096];
  int bid = blockIdx.x, t = threadIdx.x;
  if (bid < 384) {
    int h = bid & 7, dc = (bid >> 3) % 3, mb = bid / 24;
    int m0 = mb * 16;
    {  // staging: 1024 floats = 256 float4, one per thread
      int r = t >> 4, c4 = (t & 15) * 4;
      int i = h * HD + c4;
      size_t off = (size_t)(m0 + r) * INNER + i;
      float4 q0 = ldf4(qp + off), q1 = ldf4(qp + 131072 + off);
      float4 q2 = ldf4(qp + 262144 + off), q3 = ldf4(qp + 393216 + off);
      float4 bq4 = ldf4(bq + i);
      float4 s;
      s.x = q0.x + q1.x + q2.x + q3.x + bq4.x;
      s.y = q0.y + q1.y + q2.y + q3.y + bq4.y;
      s.z = q0.z + q1.z + q2.z + q3.z + bq4.z;
      s.w = q0.w + q1.w + q2.w + q3.w + bq4.w;
      ((float4*)SB)[t] = s;
    }
    __syncthreads();
    int kl = t & 63, wid = t >> 6, rg = wid & 1, kh = wid >> 1;
    int col = dc * 256 + 4 * kl;
    float4 acc[8] = {};
    gcore8<32, DD>(SB + (rg * 8) * HD + kh * 32, HD,
                   WkT + (size_t)(h * HD + kh * 32) * DD + col, acc);
    kred(acc, SB, wid, kl);
    if (!kh) {
#pragma unroll
      for (int j = 0; j < 8; j++) {
        int m = m0 + rg * 8 + j;
        const float* mkp = cp + (size_t)m * 2816 + 768 + col;
        float4 o = {acc[j].x * (mkp[0] + 1.0f), acc[j].y * (mkp[1] + 1.0f),
                    acc[j].z * (mkp[2] + 1.0f), acc[j].w * (mkp[3] + 1.0f)};
        *(float4*)(qm + ((size_t)m * NH + h) * DD + col) = o;
      }
    }
  } else {  // ---- qbk ----
    int m = bid - 384;
    if (t < 128) {
      size_t off = (size_t)m * INNER + 4 * t;
      float4 q0 = ldf4(qp + off), q1 = ldf4(qp + 131072 + off);
      float4 q2 = ldf4(qp + 262144 + off), q3 = ldf4(qp + 393216 + off);
      float4 bq4 = ldf4(bq + 4 * t), bk4 = ldf4(bk + 4 * t);
      float4 s;
      s.x = (q0.x + q1.x + q2.x + q3.x + bq4.x) * bk4.x;
      s.y = (q0.y + q1.y + q2.y + q3.y + bq4.y) * bk4.y;
      s.z = (q0.z + q1.z + q2.z + q3.z + bq4.z) * bk4.z;
      s.w = (q0.w + q1.w + q2.w + q3.w + bq4.w) * bk4.w;
      ((float4*)SB)[t] = s;
    }
    __syncthreads();
    if (t < 8) {
      float a = 0.f;
      for (int c = 0; c < HD; c++) a += SB[t * HD + c];
      qbk[m * NH + t] = a;
    }
  }
}

// ===== Stage 4: scores partial (512 blocks, Kc=192, 96/half) ===============
__global__ __launch_bounds__(256, 4) void k_s4(
    const float* __restrict__ qm, const float* __restrict__ sT,
    float* __restrict__ scp) {
  __shared__ __align__(16) float SB[4096];
  int bid = blockIdx.x, t = threadIdx.x;
  int ks = bid & 3, b = (bid >> 2) & 3, mb = bid >> 4;
  int gi0 = b * 512 + mb * 16, k0 = ks * 192;
#pragma unroll
  for (int p = 0; p < 12; p++) {
    int idx = p * 256 + t, r = idx / 192, k = idx % 192;
    SB[idx] = qm[(size_t)(gi0 + r) * DD + k0 + k];
  }
  __syncthreads();
  int kl = t & 63, wid = t >> 6, rg = wid & 1, kh = wid >> 1;
  int col = 4 * kl;
  float4 acc[8] = {};
  gcore8<96, VV>(SB + (rg * 8) * 192 + kh * 96, 192,
                 sT + ((size_t)b * DD + k0 + kh * 96) * VV + col, acc);
  kred(acc, SB, wid, kl);
  if (!kh) {
    float* dst = scp + (size_t)ks * (2048 * VV);
#pragma unroll
    for (int j = 0; j < 8; j++)
      *(float4*)(dst + (size_t)(gi0 + rg * 8 + j) * VV + col) = acc[j];
  }
}

// ===== Stage 5: softmax + ws GEMM (384 blocks, K=256, 128/half) ============
__global__ __launch_bounds__(256, 4) void k_s5(
    const float* __restrict__ scp, const float* __restrict__ qbk,
    const float* __restrict__ s_ln, const float* __restrict__ cp,
    float* __restrict__ wsm) {
  __shared__ __align__(16) float SC[4096];
  int bid = blockIdx.x, t = threadIdx.x;
  int dc = bid % 3, up = (bid / 3) % 32, b = bid / 96;
  int gi0 = b * 512 + up * 16;
  float4* SC4 = (float4*)SC;
#pragma unroll
  for (int p = 0; p < 4; p++) {
    int idx4 = p * 256 + t;
    int r = idx4 >> 6, c4 = (idx4 & 63) * 4;
    size_t o = (size_t)(gi0 + r) * VV + c4;
    float4 v0 = ldf4(scp + o), v1 = ldf4(scp + 524288 + o);
    float4 v2 = ldf4(scp + 1048576 + o), v3 = ldf4(scp + 1572864 + o);
    int m = b * 64 + up * 2 + (r >> 3), h = r & 7;
    float qb = qbk[m * NH + h];
    float4 s;
    s.x = (v0.x + v1.x + v2.x + v3.x + qb) * 0.125f;
    s.y = (v0.y + v1.y + v2.y + v3.y + qb) * 0.125f;
    s.z = (v0.z + v1.z + v2.z + v3.z + qb) * 0.125f;
    s.w = (v0.w + v1.w + v2.w + v3.w + qb) * 0.125f;
    SC4[idx4] = s;
  }
  __syncthreads();
  int wid = t >> 6, lane = t & 63;
#pragma unroll
  for (int j = 0; j < 4; j++) {
    int r = wid * 4 + j;
    float x0 = SC[r * 256 + lane],       x1 = SC[r * 256 + lane + 64];
    float x2 = SC[r * 256 + lane + 128], x3 = SC[r * 256 + lane + 192];
    float mx = fmaxf(fmaxf(x0, x1), fmaxf(x2, x3));
    for (int o = 1; o < 64; o <<= 1) mx = fmaxf(mx, __shfl_xor(mx, o, 64));
    float e0 = __expf(x0 - mx), e1 = __expf(x1 - mx);
    float e2 = __expf(x2 - mx), e3 = __expf(x3 - mx);
    float sm = e0 + e1 + e2 + e3;
    for (int o = 1; o < 64; o <<= 1) sm += __shfl_xor(sm, o, 64);
    float rinv = 1.0f / sm;
    SC[r * 256 + lane] = e0 * rinv;       SC[r * 256 + lane + 64] = e1 * rinv;
    SC[r * 256 + lane + 128] = e2 * rinv; SC[r * 256 + lane + 192] = e3 * rinv;
  }
  __syncthreads();
  int kl = t & 63, rg = wid & 1, kh = wid >> 1;
  int col = dc * 256 + 4 * kl;
  float4 acc[8] = {};
  gcore8<128, DD>(SC + (rg * 8) * 256 + kh * 128, 256,
                  s_ln + (size_t)(b * VV + kh * 128) * DD + col, acc);
  kred(acc, SC, wid, kl);
  if (!kh) {
#pragma unroll
    for (int j = 0; j < 8; j++) {
      // row r = rg*8+j -> head j, u-slot rg
      int m = b * 64 + up * 2 + rg;
      const float* mvp = cp + (size_t)m * 2816 + 1536 + col;
      float4 o = {acc[j].x * (mvp[0] + 1.0f), acc[j].y * (mvp[1] + 1.0f),
                  acc[j].z * (mvp[2] + 1.0f), acc[j].w * (mvp[3] + 1.0f)};
      *(float4*)(wsm + ((size_t)j * 256 + m) * DD + col) = o;
    }
  }
}

// ===== Stage 6: msg partial (256 blocks, Kc=96, 48/half) ===================
__global__ __launch_bounds__(256, 4) void k_s6(
    const float* __restrict__ wsm, const float* __restrict__ Wv,
    float* __restrict__ mmp) {
  __shared__ __align__(16) float AL[6144];
  int bid = blockIdx.x, t = threadIdx.x;
  int hp = bid & 1, ks = (bid >> 1) & 7, mb = bid >> 4;
  int h0 = hp * 4, m0 = mb * 16, k0 = ks * 96;
#pragma unroll
  for (int p = 0; p < 24; p++) {
    int idx = p * 256 + t;
    int e = idx / 1536, rem = idx % 1536, r = rem / 96, k = rem % 96;
    AL[idx] = wsm[((size_t)(h0 + e) * 256 + m0 + r) * DD + k0 + k];
  }
  __syncthreads();
  int kl = t & 63, wid = t >> 6, rg = wid & 1, kh = wid >> 1;
  int hs = kl >> 4, c4 = 4 * (kl & 15);
  int colg = h0 * HD + hs * HD + c4;
  const float* Aw = AL + hs * 1536 + (rg * 8) * 96 + kh * 48;
  float4 acc[8] = {};
  gcore8<48, INNER>(Aw, 96, Wv + (size_t)(k0 + kh * 48) * INNER + colg, acc);
  kred(acc, AL, wid, kl);
  if (!kh) {
    float* dst = mmp + (size_t)ks * (256 * INNER);
#pragma unroll
    for (int j = 0; j < 8; j++)
      *(float4*)(dst + (size_t)(m0 + rg * 8 + j) * INNER + colg) = acc[j];
  }
}

// ===== Stage 7: out partial (384 blocks, Kc=64, 32/half) ===================
__global__ __launch_bounds__(256, 4) void k_s7(
    const float* __restrict__ mmp, const float* __restrict__ bvv,
    const float* __restrict__ cp, const float* __restrict__ We,
    float* __restrict__ op) {
  __shared__ __align__(16) float AL[4096];
  int bid = blockIdx.x, t = threadIdx.x;
  int ks = bid & 7, dc = (bid >> 3) % 3, mb = bid / 24;
  int m0 = mb * 16, k0 = ks * 64;
  {  // staging: 1024 floats = 256 float4, one per thread
    int r = t >> 4, k4 = (t & 15) * 4;
    int i = k0 + k4;
    size_t off = (size_t)(m0 + r) * INNER + i;
    float4 v = ldf4(mmp + off);
    float4 m1 = ldf4(mmp + 131072 + off), m2 = ldf4(mmp + 262144 + off);
    float4 m3 = ldf4(mmp + 393216 + off), m4 = ldf4(mmp + 524288 + off);
    float4 m5 = ldf4(mmp + 655360 + off), m6 = ldf4(mmp + 786432 + off);
    float4 m7 = ldf4(mmp + 917504 + off);
    v.x = v.x + m1.x + m2.x + m3.x + m4.x + m5.x + m6.x + m7.x;
    v.y = v.y + m1.y + m2.y + m3.y + m4.y + m5.y + m6.y + m7.y;
    v.z = v.z + m1.z + m2.z + m3.z + m4.z + m5.z + m6.z + m7.z;
    v.w = v.w + m1.w + m2.w + m3.w + m4.w + m5.w + m6.w + m7.w;
    float4 me = ldf4(cp + (size_t)(m0 + r) * 2816 + 2304 + i);
    float4 bv4 = ldf4(bvv + i);
    float4 res = {(v.x + bv4.x) * (me.x + 1.0f), (v.y + bv4.y) * (me.y + 1.0f),
                  (v.z + bv4.z) * (me.z + 1.0f), (v.w + bv4.w) * (me.w + 1.0f)};
    ((float4*)AL)[t] = res;
  }
  __syncthreads();
  int kl = t & 63, wid = t >> 6, rg = wid & 1, kh = wid >> 1;
  int col = dc * 256 + 4 * kl;
  float4 acc[8] = {};
  gcore8<32, DD>(AL + (rg * 8) * 64 + kh * 32, 64,
                 We + (size_t)(k0 + kh * 32) * DD + col, acc);
  kred(acc, AL, wid, kl);
  if (!kh) {
    float* dst = op + (size_t)ks * (256 * DD);
#pragma unroll
    for (int j = 0; j < 8; j++)
      *(float4*)(dst + (size_t)(m0 + rg * 8 + j) * DD + col) = acc[j];
  }
}

// ===== Stage 8: epilogue (256 blocks, float4) ==============================
__global__ __launch_bounds__(256, 4) void k_s8(
    const float* __restrict__ op, const float* __restrict__ be,
    const float* __restrict__ gamma, const float* __restrict__ rs,
    float* __restrict__ outp) {
  int m = blockIdx.x, t = threadIdx.x;
  if (t < 192) {
    int d = 4 * t;
    size_t off = (size_t)m * DD + d;
    float4 v = ldf4(op + off);
    float4 o1 = ldf4(op + 196608 + off), o2 = ldf4(op + 393216 + off);
    float4 o3 = ldf4(op + 589824 + off), o4 = ldf4(op + 786432 + off);
    float4 o5 = ldf4(op + 983040 + off), o6 = ldf4(op + 1179648 + off);
    float4 o7 = ldf4(op + 1376256 + off);
    v.x = v.x + o1.x + o2.x + o3.x + o4.x + o5.x + o6.x + o7.x;
    v.y = v.y + o1.y + o2.y + o3.y + o4.y + o5.y + o6.y + o7.y;
    v.z = v.z + o1.z + o2.z + o3.z + o4.z + o5.z + o6.z + o7.z;
    v.w = v.w + o1.w + o2.w + o3.w + o4.w + o5.w + o6.w + o7.w;
    float4 bev = ldf4(be + d), gv = ldf4(gamma + d);
    float4 rv = ldf4(rs + off);
    float4 out = {rv.x + (v.x + bev.x) * gv.x, rv.y + (v.y + bev.y) * gv.y,
                  rv.z + (v.z + bev.z) * gv.z, rv.w + (v.w + bev.w) * gv.w};
    *(float4*)(outp + off) = out;
  }
}

extern "C" void kernel_launch(void* const* d_in, const int* in_sizes, int n_in,
                              void* d_out, int out_size, void* d_ws, size_t ws_size,
                              hipStream_t stream) {
  const float* rs     = (const float*)d_in[0];
  const float* codes  = (const float*)d_in[1];
  const float* ss     = (const float*)d_in[2];
  const float* ln_r_g = (const float*)d_in[3];
  const float* ln_r_b = (const float*)d_in[4];
  const float* ln_s_g = (const float*)d_in[5];
  const float* ln_s_b = (const float*)d_in[6];
  const float* Wq  = (const float*)d_in[7];
  const float* bq  = (const float*)d_in[8];
  const float* Wk  = (const float*)d_in[10];
  const float* bk  = (const float*)d_in[11];
  const float* Wmq = (const float*)d_in[9];
  const float* Wmk = (const float*)d_in[12];
  const float* Wv  = (const float*)d_in[13];
  const float* bv  = (const float*)d_in[14];
  const float* Wmv = (const float*)d_in[15];
  const float* We  = (const float*)d_in[16];
  const float* be  = (const float*)d_in[17];
  const float* Wme = (const float*)d_in[18];
  const float* gamma = (const float*)d_in[19];

  float* w = (float*)d_ws;
  // liveness-aliased layout (float offsets); peak ≈ 28.3 MB
  float* s_ln = w;                  // @0        786432  (s1 -> s5)
  float* r_ln = w + 786432;         //           196608  (s1 -> s2)
  float* WkT  = w + 983040;         //           393216  (s1 -> s3)
  float* qp   = w + 1376256;        //           524288  (s2 -> s3, 4 partials)
  float* sT   = w + 1900544;        //           786432  (s2 -> s4)
  float* cp   = w + 2686976;        //           720896  (s1 -> s7) [m][2816]
  float* qbk  = w + 3407872;        //             2048  (s3 -> s5)
  float* qm   = w + 3409920;        //          1572864  (s3 -> s4)
  float* scp  = w + 4982784;        //          2097152  (s4 -> s5, 4 partials)
  float* wsm  = qm;                 // alias (s5 -> s6)
  float* mmp  = r_ln;               // alias r_ln+WkT+qp region (s6 -> s7, 8 partials)
  float* op   = scp;                // alias (s7 -> s8, 8 partials)

  k_s1<<<dim3(1552), 256, 0, stream>>>(ss, rs, ln_s_g, ln_s_b, ln_r_g, ln_r_b,
                                       codes, Wmq, Wmk, Wmv, Wme, Wk,
                                       s_ln, r_ln, cp, WkT);
  k_s2<<<dim3(320), 256, 0, stream>>>(s_ln, r_ln, cp, Wq, sT, qp);
  k_s3<<<dim3(640), 256, 0, stream>>>(qp, bq, WkT, cp, bk, qm, qbk);
  k_s4<<<dim3(512), 256, 0, stream>>>(qm, sT, scp);
  k_s5<<<dim3(384), 256, 0, stream>>>(scp, qbk, s_ln, cp, wsm);
  k_s6<<<dim3(256), 256, 0, stream>>>(wsm, Wv, mmp);
  k_s7<<<dim3(384), 256, 0, stream>>>(mmp, bv, cp, We, op);
  k_s8<<<dim3(256), 256, 0, stream>>>(op, be, gamma, rs, (float*)d_out);
}

// Round 9
// 323.090 us; speedup vs baseline: 1.6817x; 1.6817x over previous
//
#include <hip/hip_runtime.h>

// ReadInAttention — v8: v3's 8-stage pipeline at 3 blocks/CU.
// v7's __launch_bounds__(256,4) forced VGPR=64 -> dual 8-deep B prefetch
// spilled (k_s1 WRITE 110MB, 543us). (256,3) caps at 170 VGPR: compiler's
// natural ~128 fits spill-free, with 12 waves/CU (1.5x v3's TLP).
// Stage bodies identical to v7 (= v3 + float4-vectorized partial staging,
// numerics verified in v5/v6).

#define DD 768
#define CDIM 384
#define NH 8
#define HD 64
#define INNER 512
#define VV 256

__device__ __forceinline__ float4 ldf4(const float* p) {
  return *(const float4*)(p);
}

__device__ __forceinline__ void fma4(float4& a, float s, const float4& b) {
  a.x += s * b.x; a.y += s * b.y; a.z += s * b.z; a.w += s * b.w;
}

// 8 rows x 8 k FMA block. A fragments as float4 pairs (2 rows at a time).
__device__ __forceinline__ void fma_chunk8(const float* __restrict__ Aw,
                                           int lda, int kk, const float4* b,
                                           float4* acc) {
#pragma unroll
  for (int rg = 0; rg < 4; rg++) {
    const float* ap = Aw + (rg * 2) * lda + kk;
    float4 a0l = ldf4(ap);
    float4 a0h = ldf4(ap + 4);
    float4 a1l = ldf4(ap + lda);
    float4 a1h = ldf4(ap + lda + 4);
    float4* ac = acc + rg * 2;
    fma4(ac[0], a0l.x, b[0]); fma4(ac[1], a1l.x, b[0]);
    fma4(ac[0], a0l.y, b[1]); fma4(ac[1], a1l.y, b[1]);
    fma4(ac[0], a0l.z, b[2]); fma4(ac[1], a1l.z, b[2]);
    fma4(ac[0], a0l.w, b[3]); fma4(ac[1], a1l.w, b[3]);
    fma4(ac[0], a0h.x, b[4]); fma4(ac[1], a1h.x, b[4]);
    fma4(ac[0], a0h.y, b[5]); fma4(ac[1], a1h.y, b[5]);
    fma4(ac[0], a0h.z, b[6]); fma4(ac[1], a1h.z, b[6]);
    fma4(ac[0], a0h.w, b[7]); fma4(ac[1], a1h.w, b[7]);
  }
}

// Per-wave GEMM over a K-half: 8 rows x (64 lanes * float4) cols.
// KQ = K/2, multiple of 16. Aw/Bp pre-offset to this wave's rows/K-half.
template <int KQ, int NS>
__device__ __forceinline__ void gcore8(const float* __restrict__ Aw, int lda,
                                       const float* __restrict__ Bp,
                                       float4* acc) {
  float4 b0[8], b1[8];
  const float* Bq = Bp;
#pragma unroll
  for (int i = 0; i < 8; i++) b0[i] = ldf4(Bq + (size_t)i * NS);
  Bq += (size_t)8 * NS;
#pragma unroll 1
  for (int kk = 0; kk + 16 <= KQ; kk += 16) {
#pragma unroll
    for (int i = 0; i < 8; i++) b1[i] = ldf4(Bq + (size_t)i * NS);
    Bq += (size_t)8 * NS;
    fma_chunk8(Aw, lda, kk, b0, acc);
    if (kk + 16 < KQ) {
#pragma unroll
      for (int i = 0; i < 8; i++) b0[i] = ldf4(Bq + (size_t)i * NS);
      Bq += (size_t)8 * NS;
    }
    fma_chunk8(Aw, lda, kk + 8, b1, acc);
  }
}

// Cross-K-half reduce via LDS. After: wave 0 holds rows 0-7, wave 1 rows
// 8-15 (kh==0); waves 2,3 done.
__device__ __forceinline__ void kred(float4* acc, float* RED, int wid,
                                     int kl) {
  __syncthreads();
  float4* R4 = (float4*)RED;
  int rg = wid & 1, kh = wid >> 1;
  if (kh) {
#pragma unroll
    for (int r = 0; r < 8; r++) R4[(rg * 8 + r) * 64 + kl] = acc[r];
  }
  __syncthreads();
  if (!kh) {
#pragma unroll
    for (int r = 0; r < 8; r++) {
      float4 v = R4[(rg * 8 + r) * 64 + kl];
      acc[r].x += v.x; acc[r].y += v.y; acc[r].z += v.z; acc[r].w += v.w;
    }
  }
}

// ===== Stage 1: code GEMM [0,176) | WkT [176,272) | LN [272,1552) ==========
__global__ __launch_bounds__(256, 3) void k_s1(
    const float* __restrict__ ss, const float* __restrict__ rs,
    const float* __restrict__ g_s, const float* __restrict__ b_s,
    const float* __restrict__ g_r, const float* __restrict__ b_r,
    const float* __restrict__ codes, const float* __restrict__ Wmq,
    const float* __restrict__ Wmk, const float* __restrict__ Wmv,
    const float* __restrict__ Wme, const float* __restrict__ Wk,
    float* __restrict__ s_ln, float* __restrict__ r_ln,
    float* __restrict__ cp, float* __restrict__ WkT) {
  __shared__ __align__(16) float SB[6144];
  int bid = blockIdx.x, t = threadIdx.x;
  if (bid < 176) {  // ---- code GEMM: 16 rows x 256 cols, K=384 (192/half) --
    int nc = bid % 11, mb = bid / 11;
    int base = nc * 256;
    const float* W; int N, colW;
    if (base < 768)       { W = Wmq; N = DD;    colW = base; }
    else if (base < 1536) { W = Wmk; N = DD;    colW = base - 768; }
    else if (base < 2304) { W = Wmv; N = DD;    colW = base - 1536; }
    else                  { W = Wme; N = INNER; colW = base - 2304; }
    int m0 = mb * 16;
#pragma unroll
    for (int p = 0; p < 24; p++) {
      int idx = p * 256 + t, r = idx / 384, k = idx % 384;
      SB[idx] = codes[(size_t)(m0 + r) * CDIM + k];
    }
    __syncthreads();
    int kl = t & 63, wid = t >> 6, rg = wid & 1, kh = wid >> 1;
    float4 acc[8] = {};
    const float* Aw = SB + (rg * 8) * 384 + kh * 192;
    if (N == DD)
      gcore8<192, DD>(Aw, 384, W + (size_t)(kh * 192) * DD + colW + 4 * kl, acc);
    else
      gcore8<192, INNER>(Aw, 384, W + (size_t)(kh * 192) * INNER + colW + 4 * kl, acc);
    kred(acc, SB, wid, kl);
    if (!kh) {
      int gcol = base + 4 * kl;
#pragma unroll
      for (int j = 0; j < 8; j++)
        *(float4*)(cp + (size_t)(m0 + rg * 8 + j) * 2816 + gcol) = acc[j];
    }
  } else if (bid < 272) {  // ---- Wk transpose ----
    int tid = bid - 176;
    int d0 = (tid >> 3) * 64, c0 = (tid & 7) * 64;
    int j = t & 63, i0 = t >> 6;
#pragma unroll
    for (int p = 0; p < 16; p++) {
      int i = p * 4 + i0;
      SB[i * 65 + j] = Wk[(size_t)(d0 + i) * INNER + c0 + j];
    }
    __syncthreads();
#pragma unroll
    for (int p = 0; p < 16; p++) {
      int i = p * 4 + i0;
      WkT[(size_t)(c0 + i) * DD + d0 + j] = SB[j * 65 + i];
    }
  } else {  // ---- LayerNorm ----
    int rr = bid - 272;
    const float *x, *g, *bb; float* y; int r;
    if (rr < 1024) { x = ss; g = g_s; bb = b_s; y = s_ln; r = rr; }
    else           { x = rs; g = g_r; bb = b_r; y = r_ln; r = rr - 1024; }
    const float* xr = x + (size_t)r * DD;
    float v0 = xr[t], v1 = xr[t + 256], v2 = xr[t + 512];
    float s = v0 + v1 + v2, sq = v0 * v0 + v1 * v1 + v2 * v2;
    for (int o = 32; o > 0; o >>= 1) {
      s += __shfl_down(s, o, 64); sq += __shfl_down(sq, o, 64);
    }
    int wid = t >> 6, lane = t & 63;
    if (lane == 0) { SB[wid] = s; SB[wid + 4] = sq; }
    __syncthreads();
    float sum = SB[0] + SB[1] + SB[2] + SB[3];
    float ssq = SB[4] + SB[5] + SB[6] + SB[7];
    float mu = sum * (1.0f / 768.0f);
    float var = ssq * (1.0f / 768.0f) - mu * mu;
    float rstd = rsqrtf(var + 1e-5f);
    float* yr = y + (size_t)r * DD;
    yr[t]       = (v0 - mu) * rstd * g[t]       + bb[t];
    yr[t + 256] = (v1 - mu) * rstd * g[t + 256] + bb[t + 256];
    yr[t + 512] = (v2 - mu) * rstd * g[t + 512] + bb[t + 512];
  }
}

// ===== Stage 2: q partial [0,128) (Kc=192, 96/half) | sT [128,320) =========
__global__ __launch_bounds__(256, 3) void k_s2(
    const float* __restrict__ s_ln, const float* __restrict__ r_ln,
    const float* __restrict__ cp, const float* __restrict__ Wq,
    float* __restrict__ sT, float* __restrict__ qp) {
  __shared__ __align__(16) float SB[4160];
  int bid = blockIdx.x, t = threadIdx.x;
  if (bid < 128) {
    int ks = bid & 3, tile = bid >> 2, nc = tile & 1, mb = tile >> 1;
    int m0 = mb * 16, col0 = nc * 256, k0 = ks * 192;
#pragma unroll
    for (int p = 0; p < 12; p++) {
      int idx = p * 256 + t, r = idx / 192, k = idx % 192;
      int d = k0 + k;
      float mqv = cp[(size_t)(m0 + r) * 2816 + d] + 1.0f;
      SB[idx] = r_ln[(size_t)(m0 + r) * DD + d] * mqv;
    }
    __syncthreads();
    int kl = t & 63, wid = t >> 6, rg = wid & 1, kh = wid >> 1;
    int col = col0 + 4 * kl;
    float4 acc[8] = {};
    gcore8<96, INNER>(SB + (rg * 8) * 192 + kh * 96, 192,
                      Wq + (size_t)(k0 + kh * 96) * INNER + col, acc);
    kred(acc, SB, wid, kl);
    if (!kh) {
      float* dst = qp + (size_t)ks * (256 * INNER);
#pragma unroll
      for (int j = 0; j < 8; j++)
        *(float4*)(dst + (size_t)(m0 + rg * 8 + j) * INNER + col) = acc[j];
    }
  } else {  // ---- sT[b][d][v] ----
    int tid = bid - 128;
    int vt = tid & 3, dt = (tid >> 2) % 12, b = tid / 48;
    int v0 = vt * 64, d0 = dt * 64;
    int j = t & 63, i0 = t >> 6;
#pragma unroll
    for (int p = 0; p < 16; p++) {
      int i = p * 4 + i0;
      SB[i * 65 + j] = s_ln[(size_t)(b * VV + v0 + i) * DD + d0 + j];
    }
    __syncthreads();
#pragma unroll
    for (int p = 0; p < 16; p++) {
      int i = p * 4 + i0;
      sT[((size_t)b * DD + d0 + i) * VV + v0 + j] = SB[j * 65 + i];
    }
  }
}

// ===== Stage 3: qmk [0,384) (K=64, 32/half) | qbk [384,640) ================
__global__ __launch_bounds__(256, 3) void k_s3(
    const float* __restrict__ qp, const float* __restrict__ bq,
    const float* __restrict__ WkT, const float* __restrict__ cp,
    const float* __restrict__ bk, float* __restrict__ qm,
    float* __restrict__ qbk) {
  __shared__ __align__(16) float SB[4096];
  int bid = blockIdx.x, t = threadIdx.x;
  if (bid < 384) {
    int h = bid & 7, dc = (bid >> 3) % 3, mb = bid / 24;
    int m0 = mb * 16;
    {  // staging: 1024 floats = 256 float4, one per thread
      int r = t >> 4, c4 = (t & 15) * 4;
      int i = h * HD + c4;
      size_t off = (size_t)(m0 + r) * INNER + i;
      float4 q0 = ldf4(qp + off), q1 = ldf4(qp + 131072 + off);
      float4 q2 = ldf4(qp + 262144 + off), q3 = ldf4(qp + 393216 + off);
      float4 bq4 = ldf4(bq + i);
      float4 s;
      s.x = q0.x + q1.x + q2.x + q3.x + bq4.x;
      s.y = q0.y + q1.y + q2.y + q3.y + bq4.y;
      s.z = q0.z + q1.z + q2.z + q3.z + bq4.z;
      s.w = q0.w + q1.w + q2.w + q3.w + bq4.w;
      ((float4*)SB)[t] = s;
    }
    __syncthreads();
    int kl = t & 63, wid = t >> 6, rg = wid & 1, kh = wid >> 1;
    int col = dc * 256 + 4 * kl;
    float4 acc[8] = {};
    gcore8<32, DD>(SB + (rg * 8) * HD + kh * 32, HD,
                   WkT + (size_t)(h * HD + kh * 32) * DD + col, acc);
    kred(acc, SB, wid, kl);
    if (!kh) {
#pragma unroll
      for (int j = 0; j < 8; j++) {
        int m = m0 + rg * 8 + j;
        const float* mkp = cp + (size_t)m * 2816 + 768 + col;
        float4 o = {acc[j].x * (mkp[0] + 1.0f), acc[j].y * (mkp[1] + 1.0f),
                    acc[j].z * (mkp[2] + 1.0f), acc[j].w * (mkp[3] + 1.0f)};
        *(float4*)(qm + ((size_t)m * NH + h) * DD + col) = o;
      }
    }
  } else {  // ---- qbk ----
    int m = bid - 384;
    if (t < 128) {
      size_t off = (size_t)m * INNER + 4 * t;
      float4 q0 = ldf4(qp + off), q1 = ldf4(qp + 131072 + off);
      float4 q2 = ldf4(qp + 262144 + off), q3 = ldf4(qp + 393216 + off);
      float4 bq4 = ldf4(bq + 4 * t), bk4 = ldf4(bk + 4 * t);
      float4 s;
      s.x = (q0.x + q1.x + q2.x + q3.x + bq4.x) * bk4.x;
      s.y = (q0.y + q1.y + q2.y + q3.y + bq4.y) * bk4.y;
      s.z = (q0.z + q1.z + q2.z + q3.z + bq4.z) * bk4.z;
      s.w = (q0.w + q1.w + q2.w + q3.w + bq4.w) * bk4.w;
      ((float4*)SB)[t] = s;
    }
    __syncthreads();
    if (t < 8) {
      float a = 0.f;
      for (int c = 0; c < HD; c++) a += SB[t * HD + c];
      qbk[m * NH + t] = a;
    }
  }
}

// ===== Stage 4: scores partial (512 blocks, Kc=192, 96/half) ===============
__global__ __launch_bounds__(256, 3) void k_s4(
    const float* __restrict__ qm, const float* __restrict__ sT,
    float* __restrict__ scp) {
  __shared__ __align__(16) float SB[4096];
  int bid = blockIdx.x, t = threadIdx.x;
  int ks = bid & 3, b = (bid >> 2) & 3, mb = bid >> 4;
  int gi0 = b * 512 + mb * 16, k0 = ks * 192;
#pragma unroll
  for (int p = 0; p < 12; p++) {
    int idx = p * 256 + t, r = idx / 192, k = idx % 192;
    SB[idx] = qm[(size_t)(gi0 + r) * DD + k0 + k];
  }
  __syncthreads();
  int kl = t & 63, wid = t >> 6, rg = wid & 1, kh = wid >> 1;
  int col = 4 * kl;
  float4 acc[8] = {};
  gcore8<96, VV>(SB + (rg * 8) * 192 + kh * 96, 192,
                 sT + ((size_t)b * DD + k0 + kh * 96) * VV + col, acc);
  kred(acc, SB, wid, kl);
  if (!kh) {
    float* dst = scp + (size_t)ks * (2048 * VV);
#pragma unroll
    for (int j = 0; j < 8; j++)
      *(float4*)(dst + (size_t)(gi0 + rg * 8 + j) * VV + col) = acc[j];
  }
}

// ===== Stage 5: softmax + ws GEMM (384 blocks, K=256, 128/half) ============
__global__ __launch_bounds__(256, 3) void k_s5(
    const float* __restrict__ scp, const float* __restrict__ qbk,
    const float* __restrict__ s_ln, const float* __restrict__ cp,
    float* __restrict__ wsm) {
  __shared__ __align__(16) float SC[4096];
  int bid = blockIdx.x, t = threadIdx.x;
  int dc = bid % 3, up = (bid / 3) % 32, b = bid / 96;
  int gi0 = b * 512 + up * 16;
  float4* SC4 = (float4*)SC;
#pragma unroll
  for (int p = 0; p < 4; p++) {
    int idx4 = p * 256 + t;
    int r = idx4 >> 6, c4 = (idx4 & 63) * 4;
    size_t o = (size_t)(gi0 + r) * VV + c4;
    float4 v0 = ldf4(scp + o), v1 = ldf4(scp + 524288 + o);
    float4 v2 = ldf4(scp + 1048576 + o), v3 = ldf4(scp + 1572864 + o);
    int m = b * 64 + up * 2 + (r >> 3), h = r & 7;
    float qb = qbk[m * NH + h];
    float4 s;
    s.x = (v0.x + v1.x + v2.x + v3.x + qb) * 0.125f;
    s.y = (v0.y + v1.y + v2.y + v3.y + qb) * 0.125f;
    s.z = (v0.z + v1.z + v2.z + v3.z + qb) * 0.125f;
    s.w = (v0.w + v1.w + v2.w + v3.w + qb) * 0.125f;
    SC4[idx4] = s;
  }
  __syncthreads();
  int wid = t >> 6, lane = t & 63;
#pragma unroll
  for (int j = 0; j < 4; j++) {
    int r = wid * 4 + j;
    float x0 = SC[r * 256 + lane],       x1 = SC[r * 256 + lane + 64];
    float x2 = SC[r * 256 + lane + 128], x3 = SC[r * 256 + lane + 192];
    float mx = fmaxf(fmaxf(x0, x1), fmaxf(x2, x3));
    for (int o = 1; o < 64; o <<= 1) mx = fmaxf(mx, __shfl_xor(mx, o, 64));
    float e0 = __expf(x0 - mx), e1 = __expf(x1 - mx);
    float e2 = __expf(x2 - mx), e3 = __expf(x3 - mx);
    float sm = e0 + e1 + e2 + e3;
    for (int o = 1; o < 64; o <<= 1) sm += __shfl_xor(sm, o, 64);
    float rinv = 1.0f / sm;
    SC[r * 256 + lane] = e0 * rinv;       SC[r * 256 + lane + 64] = e1 * rinv;
    SC[r * 256 + lane + 128] = e2 * rinv; SC[r * 256 + lane + 192] = e3 * rinv;
  }
  __syncthreads();
  int kl = t & 63, rg = wid & 1, kh = wid >> 1;
  int col = dc * 256 + 4 * kl;
  float4 acc[8] = {};
  gcore8<128, DD>(SC + (rg * 8) * 256 + kh * 128, 256,
                  s_ln + (size_t)(b * VV + kh * 128) * DD + col, acc);
  kred(acc, SC, wid, kl);
  if (!kh) {
#pragma unroll
    for (int j = 0; j < 8; j++) {
      // row r = rg*8+j -> head j, u-slot rg
      int m = b * 64 + up * 2 + rg;
      const float* mvp = cp + (size_t)m * 2816 + 1536 + col;
      float4 o = {acc[j].x * (mvp[0] + 1.0f), acc[j].y * (mvp[1] + 1.0f),
                  acc[j].z * (mvp[2] + 1.0f), acc[j].w * (mvp[3] + 1.0f)};
      *(float4*)(wsm + ((size_t)j * 256 + m) * DD + col) = o;
    }
  }
}

// ===== Stage 6: msg partial (256 blocks, Kc=96, 48/half) ===================
__global__ __launch_bounds__(256, 3) void k_s6(
    const float* __restrict__ wsm, const float* __restrict__ Wv,
    float* __restrict__ mmp) {
  __shared__ __align__(16) float AL[6144];
  int bid = blockIdx.x, t = threadIdx.x;
  int hp = bid & 1, ks = (bid >> 1) & 7, mb = bid >> 4;
  int h0 = hp * 4, m0 = mb * 16, k0 = ks * 96;
#pragma unroll
  for (int p = 0; p < 24; p++) {
    int idx = p * 256 + t;
    int e = idx / 1536, rem = idx % 1536, r = rem / 96, k = rem % 96;
    AL[idx] = wsm[((size_t)(h0 + e) * 256 + m0 + r) * DD + k0 + k];
  }
  __syncthreads();
  int kl = t & 63, wid = t >> 6, rg = wid & 1, kh = wid >> 1;
  int hs = kl >> 4, c4 = 4 * (kl & 15);
  int colg = h0 * HD + hs * HD + c4;
  const float* Aw = AL + hs * 1536 + (rg * 8) * 96 + kh * 48;
  float4 acc[8] = {};
  gcore8<48, INNER>(Aw, 96, Wv + (size_t)(k0 + kh * 48) * INNER + colg, acc);
  kred(acc, AL, wid, kl);
  if (!kh) {
    float* dst = mmp + (size_t)ks * (256 * INNER);
#pragma unroll
    for (int j = 0; j < 8; j++)
      *(float4*)(dst + (size_t)(m0 + rg * 8 + j) * INNER + colg) = acc[j];
  }
}

// ===== Stage 7: out partial (384 blocks, Kc=64, 32/half) ===================
__global__ __launch_bounds__(256, 3) void k_s7(
    const float* __restrict__ mmp, const float* __restrict__ bvv,
    const float* __restrict__ cp, const float* __restrict__ We,
    float* __restrict__ op) {
  __shared__ __align__(16) float AL[4096];
  int bid = blockIdx.x, t = threadIdx.x;
  int ks = bid & 7, dc = (bid >> 3) % 3, mb = bid / 24;
  int m0 = mb * 16, k0 = ks * 64;
  {  // staging: 1024 floats = 256 float4, one per thread
    int r = t >> 4, k4 = (t & 15) * 4;
    int i = k0 + k4;
    size_t off = (size_t)(m0 + r) * INNER + i;
    float4 v = ldf4(mmp + off);
    float4 m1 = ldf4(mmp + 131072 + off), m2 = ldf4(mmp + 262144 + off);
    float4 m3 = ldf4(mmp + 393216 + off), m4 = ldf4(mmp + 524288 + off);
    float4 m5 = ldf4(mmp + 655360 + off), m6 = ldf4(mmp + 786432 + off);
    float4 m7 = ldf4(mmp + 917504 + off);
    v.x = v.x + m1.x + m2.x + m3.x + m4.x + m5.x + m6.x + m7.x;
    v.y = v.y + m1.y + m2.y + m3.y + m4.y + m5.y + m6.y + m7.y;
    v.z = v.z + m1.z + m2.z + m3.z + m4.z + m5.z + m6.z + m7.z;
    v.w = v.w + m1.w + m2.w + m3.w + m4.w + m5.w + m6.w + m7.w;
    float4 me = ldf4(cp + (size_t)(m0 + r) * 2816 + 2304 + i);
    float4 bv4 = ldf4(bvv + i);
    float4 res = {(v.x + bv4.x) * (me.x + 1.0f), (v.y + bv4.y) * (me.y + 1.0f),
                  (v.z + bv4.z) * (me.z + 1.0f), (v.w + bv4.w) * (me.w + 1.0f)};
    ((float4*)AL)[t] = res;
  }
  __syncthreads();
  int kl = t & 63, wid = t >> 6, rg = wid & 1, kh = wid >> 1;
  int col = dc * 256 + 4 * kl;
  float4 acc[8] = {};
  gcore8<32, DD>(AL + (rg * 8) * 64 + kh * 32, 64,
                 We + (size_t)(k0 + kh * 32) * DD + col, acc);
  kred(acc, AL, wid, kl);
  if (!kh) {
    float* dst = op + (size_t)ks * (256 * DD);
#pragma unroll
    for (int j = 0; j < 8; j++)
      *(float4*)(dst + (size_t)(m0 + rg * 8 + j) * DD + col) = acc[j];
  }
}

// ===== Stage 8: epilogue (256 blocks, float4) ==============================
__global__ __launch_bounds__(256, 3) void k_s8(
    const float* __restrict__ op, const float* __restrict__ be,
    const float* __restrict__ gamma, const float* __restrict__ rs,
    float* __restrict__ outp) {
  int m = blockIdx.x, t = threadIdx.x;
  if (t < 192) {
    int d = 4 * t;
    size_t off = (size_t)m * DD + d;
    float4 v = ldf4(op + off);
    float4 o1 = ldf4(op + 196608 + off), o2 = ldf4(op + 393216 + off);
    float4 o3 = ldf4(op + 589824 + off), o4 = ldf4(op + 786432 + off);
    float4 o5 = ldf4(op + 983040 + off), o6 = ldf4(op + 1179648 + off);
    float4 o7 = ldf4(op + 1376256 + off);
    v.x = v.x + o1.x + o2.x + o3.x + o4.x + o5.x + o6.x + o7.x;
    v.y = v.y + o1.y + o2.y + o3.y + o4.y + o5.y + o6.y + o7.y;
    v.z = v.z + o1.z + o2.z + o3.z + o4.z + o5.z + o6.z + o7.z;
    v.w = v.w + o1.w + o2.w + o3.w + o4.w + o5.w + o6.w + o7.w;
    float4 bev = ldf4(be + d), gv = ldf4(gamma + d);
    float4 rv = ldf4(rs + off);
    float4 out = {rv.x + (v.x + bev.x) * gv.x, rv.y + (v.y + bev.y) * gv.y,
                  rv.z + (v.z + bev.z) * gv.z, rv.w + (v.w + bev.w) * gv.w};
    *(float4*)(outp + off) = out;
  }
}

extern "C" void kernel_launch(void* const* d_in, const int* in_sizes, int n_in,
                              void* d_out, int out_size, void* d_ws, size_t ws_size,
                              hipStream_t stream) {
  const float* rs     = (const float*)d_in[0];
  const float* codes  = (const float*)d_in[1];
  const float* ss     = (const float*)d_in[2];
  const float* ln_r_g = (const float*)d_in[3];
  const float* ln_r_b = (const float*)d_in[4];
  const float* ln_s_g = (const float*)d_in[5];
  const float* ln_s_b = (const float*)d_in[6];
  const float* Wq  = (const float*)d_in[7];
  const float* bq  = (const float*)d_in[8];
  const float* Wk  = (const float*)d_in[10];
  const float* bk  = (const float*)d_in[11];
  const float* Wmq = (const float*)d_in[9];
  const float* Wmk = (const float*)d_in[12];
  const float* Wv  = (const float*)d_in[13];
  const float* bv  = (const float*)d_in[14];
  const float* Wmv = (const float*)d_in[15];
  const float* We  = (const float*)d_in[16];
  const float* be  = (const float*)d_in[17];
  const float* Wme = (const float*)d_in[18];
  const float* gamma = (const float*)d_in[19];

  float* w = (float*)d_ws;
  // liveness-aliased layout (float offsets); peak ≈ 28.3 MB
  float* s_ln = w;                  // @0        786432  (s1 -> s5)
  float* r_ln = w + 786432;         //           196608  (s1 -> s2)
  float* WkT  = w + 983040;         //           393216  (s1 -> s3)
  float* qp   = w + 1376256;        //           524288  (s2 -> s3, 4 partials)
  float* sT   = w + 1900544;        //           786432  (s2 -> s4)
  float* cp   = w + 2686976;        //           720896  (s1 -> s7) [m][2816]
  float* qbk  = w + 3407872;        //             2048  (s3 -> s5)
  float* qm   = w + 3409920;        //          1572864  (s3 -> s4)
  float* scp  = w + 4982784;        //          2097152  (s4 -> s5, 4 partials)
  float* wsm  = qm;                 // alias (s5 -> s6)
  float* mmp  = r_ln;               // alias r_ln+WkT+qp region (s6 -> s7, 8 partials)
  float* op   = scp;                // alias (s7 -> s8, 8 partials)

  k_s1<<<dim3(1552), 256, 0, stream>>>(ss, rs, ln_s_g, ln_s_b, ln_r_g, ln_r_b,
                                       codes, Wmq, Wmk, Wmv, Wme, Wk,
                                       s_ln, r_ln, cp, WkT);
  k_s2<<<dim3(320), 256, 0, stream>>>(s_ln, r_ln, cp, Wq, sT, qp);
  k_s3<<<dim3(640), 256, 0, stream>>>(qp, bq, WkT, cp, bk, qm, qbk);
  k_s4<<<dim3(512), 256, 0, stream>>>(qm, sT, scp);
  k_s5<<<dim3(384), 256, 0, stream>>>(scp, qbk, s_ln, cp, wsm);
  k_s6<<<dim3(256), 256, 0, stream>>>(wsm, Wv, mmp);
  k_s7<<<dim3(384), 256, 0, stream>>>(mmp, bv, cp, We, op);
  k_s8<<<dim3(256), 256, 0, stream>>>(op, be, gamma, rs, (float*)d_out);
}

// Round 10
// 183.121 us; speedup vs baseline: 2.9671x; 1.7644x over previous
//
#include <hip/hip_runtime.h>

// ReadInAttention — v9: v3's proven (256,2) pipeline + grid-tail reduction.
//  - __launch_bounds__(256,2) everywhere: hipcc allocates 128 VGPR, no
//    spill (v7's (,4)->64 VGPR and v8's (,3)->84 VGPR both spilled).
//  - k_s1 LN: 4 rows/block (1/wave, shfl-only reduce) -> grid 1552->592,
//    cuts LN dispatch-tail rounds.
//  - s3: qbk folded into dc==0 qmk blocks (they already stage qsum) ->
//    grid 640->384.
//  - float4-vectorized partial staging (verified v5/v6) retained.

#define DD 768
#define CDIM 384
#define NH 8
#define HD 64
#define INNER 512
#define VV 256

__device__ __forceinline__ float4 ldf4(const float* p) {
  return *(const float4*)(p);
}

__device__ __forceinline__ void fma4(float4& a, float s, const float4& b) {
  a.x += s * b.x; a.y += s * b.y; a.z += s * b.z; a.w += s * b.w;
}

// 8 rows x 8 k FMA block. A fragments as float4 pairs (2 rows at a time).
__device__ __forceinline__ void fma_chunk8(const float* __restrict__ Aw,
                                           int lda, int kk, const float4* b,
                                           float4* acc) {
#pragma unroll
  for (int rg = 0; rg < 4; rg++) {
    const float* ap = Aw + (rg * 2) * lda + kk;
    float4 a0l = ldf4(ap);
    float4 a0h = ldf4(ap + 4);
    float4 a1l = ldf4(ap + lda);
    float4 a1h = ldf4(ap + lda + 4);
    float4* ac = acc + rg * 2;
    fma4(ac[0], a0l.x, b[0]); fma4(ac[1], a1l.x, b[0]);
    fma4(ac[0], a0l.y, b[1]); fma4(ac[1], a1l.y, b[1]);
    fma4(ac[0], a0l.z, b[2]); fma4(ac[1], a1l.z, b[2]);
    fma4(ac[0], a0l.w, b[3]); fma4(ac[1], a1l.w, b[3]);
    fma4(ac[0], a0h.x, b[4]); fma4(ac[1], a1h.x, b[4]);
    fma4(ac[0], a0h.y, b[5]); fma4(ac[1], a1h.y, b[5]);
    fma4(ac[0], a0h.z, b[6]); fma4(ac[1], a1h.z, b[6]);
    fma4(ac[0], a0h.w, b[7]); fma4(ac[1], a1h.w, b[7]);
  }
}

// Per-wave GEMM over a K-half: 8 rows x (64 lanes * float4) cols.
// KQ = K/2, multiple of 16. Aw/Bp pre-offset to this wave's rows/K-half.
template <int KQ, int NS>
__device__ __forceinline__ void gcore8(const float* __restrict__ Aw, int lda,
                                       const float* __restrict__ Bp,
                                       float4* acc) {
  float4 b0[8], b1[8];
  const float* Bq = Bp;
#pragma unroll
  for (int i = 0; i < 8; i++) b0[i] = ldf4(Bq + (size_t)i * NS);
  Bq += (size_t)8 * NS;
#pragma unroll 1
  for (int kk = 0; kk + 16 <= KQ; kk += 16) {
#pragma unroll
    for (int i = 0; i < 8; i++) b1[i] = ldf4(Bq + (size_t)i * NS);
    Bq += (size_t)8 * NS;
    fma_chunk8(Aw, lda, kk, b0, acc);
    if (kk + 16 < KQ) {
#pragma unroll
      for (int i = 0; i < 8; i++) b0[i] = ldf4(Bq + (size_t)i * NS);
      Bq += (size_t)8 * NS;
    }
    fma_chunk8(Aw, lda, kk + 8, b1, acc);
  }
}

// Cross-K-half reduce via LDS. After: wave 0 holds rows 0-7, wave 1 rows
// 8-15 (kh==0); waves 2,3 done.
__device__ __forceinline__ void kred(float4* acc, float* RED, int wid,
                                     int kl) {
  __syncthreads();
  float4* R4 = (float4*)RED;
  int rg = wid & 1, kh = wid >> 1;
  if (kh) {
#pragma unroll
    for (int r = 0; r < 8; r++) R4[(rg * 8 + r) * 64 + kl] = acc[r];
  }
  __syncthreads();
  if (!kh) {
#pragma unroll
    for (int r = 0; r < 8; r++) {
      float4 v = R4[(rg * 8 + r) * 64 + kl];
      acc[r].x += v.x; acc[r].y += v.y; acc[r].z += v.z; acc[r].w += v.w;
    }
  }
}

// ===== Stage 1: code GEMM [0,176) | WkT [176,272) | LN [272,592) ===========
__global__ __launch_bounds__(256, 2) void k_s1(
    const float* __restrict__ ss, const float* __restrict__ rs,
    const float* __restrict__ g_s, const float* __restrict__ b_s,
    const float* __restrict__ g_r, const float* __restrict__ b_r,
    const float* __restrict__ codes, const float* __restrict__ Wmq,
    const float* __restrict__ Wmk, const float* __restrict__ Wmv,
    const float* __restrict__ Wme, const float* __restrict__ Wk,
    float* __restrict__ s_ln, float* __restrict__ r_ln,
    float* __restrict__ cp, float* __restrict__ WkT) {
  __shared__ __align__(16) float SB[6144];
  int bid = blockIdx.x, t = threadIdx.x;
  if (bid < 176) {  // ---- code GEMM: 16 rows x 256 cols, K=384 (192/half) --
    int nc = bid % 11, mb = bid / 11;
    int base = nc * 256;
    const float* W; int N, colW;
    if (base < 768)       { W = Wmq; N = DD;    colW = base; }
    else if (base < 1536) { W = Wmk; N = DD;    colW = base - 768; }
    else if (base < 2304) { W = Wmv; N = DD;    colW = base - 1536; }
    else                  { W = Wme; N = INNER; colW = base - 2304; }
    int m0 = mb * 16;
#pragma unroll
    for (int p = 0; p < 24; p++) {
      int idx = p * 256 + t, r = idx / 384, k = idx % 384;
      SB[idx] = codes[(size_t)(m0 + r) * CDIM + k];
    }
    __syncthreads();
    int kl = t & 63, wid = t >> 6, rg = wid & 1, kh = wid >> 1;
    float4 acc[8] = {};
    const float* Aw = SB + (rg * 8) * 384 + kh * 192;
    if (N == DD)
      gcore8<192, DD>(Aw, 384, W + (size_t)(kh * 192) * DD + colW + 4 * kl, acc);
    else
      gcore8<192, INNER>(Aw, 384, W + (size_t)(kh * 192) * INNER + colW + 4 * kl, acc);
    kred(acc, SB, wid, kl);
    if (!kh) {
      int gcol = base + 4 * kl;
#pragma unroll
      for (int j = 0; j < 8; j++)
        *(float4*)(cp + (size_t)(m0 + rg * 8 + j) * 2816 + gcol) = acc[j];
    }
  } else if (bid < 272) {  // ---- Wk transpose ----
    int tid = bid - 176;
    int d0 = (tid >> 3) * 64, c0 = (tid & 7) * 64;
    int j = t & 63, i0 = t >> 6;
#pragma unroll
    for (int p = 0; p < 16; p++) {
      int i = p * 4 + i0;
      SB[i * 65 + j] = Wk[(size_t)(d0 + i) * INNER + c0 + j];
    }
    __syncthreads();
#pragma unroll
    for (int p = 0; p < 16; p++) {
      int i = p * 4 + i0;
      WkT[(size_t)(c0 + i) * DD + d0 + j] = SB[j * 65 + i];
    }
  } else {  // ---- LayerNorm: 4 rows/block, 1 row/wave, shfl-only reduce ----
    int rr = (bid - 272) * 4 + (t >> 6);  // < 1280
    const float *x, *g, *bb; float* y; int r;
    if (rr < 1024) { x = ss; g = g_s; bb = b_s; y = s_ln; r = rr; }
    else           { x = rs; g = g_r; bb = b_r; y = r_ln; r = rr - 1024; }
    const float* xr = x + (size_t)r * DD;
    int lane = t & 63;
    float v[12];
    float s = 0.f, sq = 0.f;
#pragma unroll
    for (int j = 0; j < 12; j++) {
      v[j] = xr[lane + 64 * j];
      s += v[j]; sq += v[j] * v[j];
    }
    for (int o = 32; o > 0; o >>= 1) {
      s += __shfl_down(s, o, 64); sq += __shfl_down(sq, o, 64);
    }
    s = __shfl(s, 0, 64); sq = __shfl(sq, 0, 64);
    float mu = s * (1.0f / 768.0f);
    float var = sq * (1.0f / 768.0f) - mu * mu;
    float rstd = rsqrtf(var + 1e-5f);
    float* yr = y + (size_t)r * DD;
#pragma unroll
    for (int j = 0; j < 12; j++) {
      int d = lane + 64 * j;
      yr[d] = (v[j] - mu) * rstd * g[d] + bb[d];
    }
  }
}

// ===== Stage 2: q partial [0,128) (Kc=192, 96/half) | sT [128,320) =========
__global__ __launch_bounds__(256, 2) void k_s2(
    const float* __restrict__ s_ln, const float* __restrict__ r_ln,
    const float* __restrict__ cp, const float* __restrict__ Wq,
    float* __restrict__ sT, float* __restrict__ qp) {
  __shared__ __align__(16) float SB[4160];
  int bid = blockIdx.x, t = threadIdx.x;
  if (bid < 128) {
    int ks = bid & 3, tile = bid >> 2, nc = tile & 1, mb = tile >> 1;
    int m0 = mb * 16, col0 = nc * 256, k0 = ks * 192;
#pragma unroll
    for (int p = 0; p < 12; p++) {
      int idx = p * 256 + t, r = idx / 192, k = idx % 192;
      int d = k0 + k;
      float mqv = cp[(size_t)(m0 + r) * 2816 + d] + 1.0f;
      SB[idx] = r_ln[(size_t)(m0 + r) * DD + d] * mqv;
    }
    __syncthreads();
    int kl = t & 63, wid = t >> 6, rg = wid & 1, kh = wid >> 1;
    int col = col0 + 4 * kl;
    float4 acc[8] = {};
    gcore8<96, INNER>(SB + (rg * 8) * 192 + kh * 96, 192,
                      Wq + (size_t)(k0 + kh * 96) * INNER + col, acc);
    kred(acc, SB, wid, kl);
    if (!kh) {
      float* dst = qp + (size_t)ks * (256 * INNER);
#pragma unroll
      for (int j = 0; j < 8; j++)
        *(float4*)(dst + (size_t)(m0 + rg * 8 + j) * INNER + col) = acc[j];
    }
  } else {  // ---- sT[b][d][v] ----
    int tid = bid - 128;
    int vt = tid & 3, dt = (tid >> 2) % 12, b = tid / 48;
    int v0 = vt * 64, d0 = dt * 64;
    int j = t & 63, i0 = t >> 6;
#pragma unroll
    for (int p = 0; p < 16; p++) {
      int i = p * 4 + i0;
      SB[i * 65 + j] = s_ln[(size_t)(b * VV + v0 + i) * DD + d0 + j];
    }
    __syncthreads();
#pragma unroll
    for (int p = 0; p < 16; p++) {
      int i = p * 4 + i0;
      sT[((size_t)b * DD + d0 + i) * VV + v0 + j] = SB[j * 65 + i];
    }
  }
}

// ===== Stage 3: qmk + folded qbk (384 blocks, K=64, 32/half) ===============
__global__ __launch_bounds__(256, 2) void k_s3(
    const float* __restrict__ qp, const float* __restrict__ bq,
    const float* __restrict__ WkT, const float* __restrict__ cp,
    const float* __restrict__ bk, float* __restrict__ qm,
    float* __restrict__ qbk) {
  __shared__ __align__(16) float SB[4096];
  int bid = blockIdx.x, t = threadIdx.x;
  int h = bid & 7, dc = (bid >> 3) % 3, mb = bid / 24;
  int m0 = mb * 16;
  {  // staging: 1024 floats = 256 float4, one per thread
    int r = t >> 4, c4 = (t & 15) * 4;
    int i = h * HD + c4;
    size_t off = (size_t)(m0 + r) * INNER + i;
    float4 q0 = ldf4(qp + off), q1 = ldf4(qp + 131072 + off);
    float4 q2 = ldf4(qp + 262144 + off), q3 = ldf4(qp + 393216 + off);
    float4 bq4 = ldf4(bq + i);
    float4 s;
    s.x = q0.x + q1.x + q2.x + q3.x + bq4.x;
    s.y = q0.y + q1.y + q2.y + q3.y + bq4.y;
    s.z = q0.z + q1.z + q2.z + q3.z + bq4.z;
    s.w = q0.w + q1.w + q2.w + q3.w + bq4.w;
    ((float4*)SB)[t] = s;
  }
  __syncthreads();
  if (dc == 0) {  // ---- folded qbk: qbk[m][h] = sum_c qsum[m][c]*bk[h*64+c]
    int m = t >> 4, cg = t & 15;
    const float* bkh = bk + h * HD;
    float p = 0.f;
#pragma unroll
    for (int c = 4 * cg; c < 4 * cg + 4; c++) p += SB[m * HD + c] * bkh[c];
    SB[1024 + t] = p;
  }
  __syncthreads();
  if (dc == 0 && t < 16) {
    float a = 0.f;
#pragma unroll
    for (int i = 0; i < 16; i++) a += SB[1024 + t * 16 + i];
    qbk[(m0 + t) * NH + h] = a;
  }
  int kl = t & 63, wid = t >> 6, rg = wid & 1, kh = wid >> 1;
  int col = dc * 256 + 4 * kl;
  float4 acc[8] = {};
  gcore8<32, DD>(SB + (rg * 8) * HD + kh * 32, HD,
                 WkT + (size_t)(h * HD + kh * 32) * DD + col, acc);
  kred(acc, SB, wid, kl);
  if (!kh) {
#pragma unroll
    for (int j = 0; j < 8; j++) {
      int m = m0 + rg * 8 + j;
      const float* mkp = cp + (size_t)m * 2816 + 768 + col;
      float4 o = {acc[j].x * (mkp[0] + 1.0f), acc[j].y * (mkp[1] + 1.0f),
                  acc[j].z * (mkp[2] + 1.0f), acc[j].w * (mkp[3] + 1.0f)};
      *(float4*)(qm + ((size_t)m * NH + h) * DD + col) = o;
    }
  }
}

// ===== Stage 4: scores partial (512 blocks, Kc=192, 96/half) ===============
__global__ __launch_bounds__(256, 2) void k_s4(
    const float* __restrict__ qm, const float* __restrict__ sT,
    float* __restrict__ scp) {
  __shared__ __align__(16) float SB[4096];
  int bid = blockIdx.x, t = threadIdx.x;
  int ks = bid & 3, b = (bid >> 2) & 3, mb = bid >> 4;
  int gi0 = b * 512 + mb * 16, k0 = ks * 192;
#pragma unroll
  for (int p = 0; p < 12; p++) {
    int idx = p * 256 + t, r = idx / 192, k = idx % 192;
    SB[idx] = qm[(size_t)(gi0 + r) * DD + k0 + k];
  }
  __syncthreads();
  int kl = t & 63, wid = t >> 6, rg = wid & 1, kh = wid >> 1;
  int col = 4 * kl;
  float4 acc[8] = {};
  gcore8<96, VV>(SB + (rg * 8) * 192 + kh * 96, 192,
                 sT + ((size_t)b * DD + k0 + kh * 96) * VV + col, acc);
  kred(acc, SB, wid, kl);
  if (!kh) {
    float* dst = scp + (size_t)ks * (2048 * VV);
#pragma unroll
    for (int j = 0; j < 8; j++)
      *(float4*)(dst + (size_t)(gi0 + rg * 8 + j) * VV + col) = acc[j];
  }
}

// ===== Stage 5: softmax + ws GEMM (384 blocks, K=256, 128/half) ============
__global__ __launch_bounds__(256, 2) void k_s5(
    const float* __restrict__ scp, const float* __restrict__ qbk,
    const float* __restrict__ s_ln, const float* __restrict__ cp,
    float* __restrict__ wsm) {
  __shared__ __align__(16) float SC[4096];
  int bid = blockIdx.x, t = threadIdx.x;
  int dc = bid % 3, up = (bid / 3) % 32, b = bid / 96;
  int gi0 = b * 512 + up * 16;
  float4* SC4 = (float4*)SC;
#pragma unroll
  for (int p = 0; p < 4; p++) {
    int idx4 = p * 256 + t;
    int r = idx4 >> 6, c4 = (idx4 & 63) * 4;
    size_t o = (size_t)(gi0 + r) * VV + c4;
    float4 v0 = ldf4(scp + o), v1 = ldf4(scp + 524288 + o);
    float4 v2 = ldf4(scp + 1048576 + o), v3 = ldf4(scp + 1572864 + o);
    int m = b * 64 + up * 2 + (r >> 3), h = r & 7;
    float qb = qbk[m * NH + h];
    float4 s;
    s.x = (v0.x + v1.x + v2.x + v3.x + qb) * 0.125f;
    s.y = (v0.y + v1.y + v2.y + v3.y + qb) * 0.125f;
    s.z = (v0.z + v1.z + v2.z + v3.z + qb) * 0.125f;
    s.w = (v0.w + v1.w + v2.w + v3.w + qb) * 0.125f;
    SC4[idx4] = s;
  }
  __syncthreads();
  int wid = t >> 6, lane = t & 63;
#pragma unroll
  for (int j = 0; j < 4; j++) {
    int r = wid * 4 + j;
    float x0 = SC[r * 256 + lane],       x1 = SC[r * 256 + lane + 64];
    float x2 = SC[r * 256 + lane + 128], x3 = SC[r * 256 + lane + 192];
    float mx = fmaxf(fmaxf(x0, x1), fmaxf(x2, x3));
    for (int o = 1; o < 64; o <<= 1) mx = fmaxf(mx, __shfl_xor(mx, o, 64));
    float e0 = __expf(x0 - mx), e1 = __expf(x1 - mx);
    float e2 = __expf(x2 - mx), e3 = __expf(x3 - mx);
    float sm = e0 + e1 + e2 + e3;
    for (int o = 1; o < 64; o <<= 1) sm += __shfl_xor(sm, o, 64);
    float rinv = 1.0f / sm;
    SC[r * 256 + lane] = e0 * rinv;       SC[r * 256 + lane + 64] = e1 * rinv;
    SC[r * 256 + lane + 128] = e2 * rinv; SC[r * 256 + lane + 192] = e3 * rinv;
  }
  __syncthreads();
  int kl = t & 63, rg = wid & 1, kh = wid >> 1;
  int col = dc * 256 + 4 * kl;
  float4 acc[8] = {};
  gcore8<128, DD>(SC + (rg * 8) * 256 + kh * 128, 256,
                  s_ln + (size_t)(b * VV + kh * 128) * DD + col, acc);
  kred(acc, SC, wid, kl);
  if (!kh) {
#pragma unroll
    for (int j = 0; j < 8; j++) {
      // row r = rg*8+j -> head j, u-slot rg
      int m = b * 64 + up * 2 + rg;
      const float* mvp = cp + (size_t)m * 2816 + 1536 + col;
      float4 o = {acc[j].x * (mvp[0] + 1.0f), acc[j].y * (mvp[1] + 1.0f),
                  acc[j].z * (mvp[2] + 1.0f), acc[j].w * (mvp[3] + 1.0f)};
      *(float4*)(wsm + ((size_t)j * 256 + m) * DD + col) = o;
    }
  }
}

// ===== Stage 6: msg partial (256 blocks, Kc=96, 48/half) ===================
__global__ __launch_bounds__(256, 2) void k_s6(
    const float* __restrict__ wsm, const float* __restrict__ Wv,
    float* __restrict__ mmp) {
  __shared__ __align__(16) float AL[6144];
  int bid = blockIdx.x, t = threadIdx.x;
  int hp = bid & 1, ks = (bid >> 1) & 7, mb = bid >> 4;
  int h0 = hp * 4, m0 = mb * 16, k0 = ks * 96;
#pragma unroll
  for (int p = 0; p < 24; p++) {
    int idx = p * 256 + t;
    int e = idx / 1536, rem = idx % 1536, r = rem / 96, k = rem % 96;
    AL[idx] = wsm[((size_t)(h0 + e) * 256 + m0 + r) * DD + k0 + k];
  }
  __syncthreads();
  int kl = t & 63, wid = t >> 6, rg = wid & 1, kh = wid >> 1;
  int hs = kl >> 4, c4 = 4 * (kl & 15);
  int colg = h0 * HD + hs * HD + c4;
  const float* Aw = AL + hs * 1536 + (rg * 8) * 96 + kh * 48;
  float4 acc[8] = {};
  gcore8<48, INNER>(Aw, 96, Wv + (size_t)(k0 + kh * 48) * INNER + colg, acc);
  kred(acc, AL, wid, kl);
  if (!kh) {
    float* dst = mmp + (size_t)ks * (256 * INNER);
#pragma unroll
    for (int j = 0; j < 8; j++)
      *(float4*)(dst + (size_t)(m0 + rg * 8 + j) * INNER + colg) = acc[j];
  }
}

// ===== Stage 7: out partial (384 blocks, Kc=64, 32/half) ===================
__global__ __launch_bounds__(256, 2) void k_s7(
    const float* __restrict__ mmp, const float* __restrict__ bvv,
    const float* __restrict__ cp, const float* __restrict__ We,
    float* __restrict__ op) {
  __shared__ __align__(16) float AL[4096];
  int bid = blockIdx.x, t = threadIdx.x;
  int ks = bid & 7, dc = (bid >> 3) % 3, mb = bid / 24;
  int m0 = mb * 16, k0 = ks * 64;
  {  // staging: 1024 floats = 256 float4, one per thread
    int r = t >> 4, k4 = (t & 15) * 4;
    int i = k0 + k4;
    size_t off = (size_t)(m0 + r) * INNER + i;
    float4 v = ldf4(mmp + off);
    float4 m1 = ldf4(mmp + 131072 + off), m2 = ldf4(mmp + 262144 + off);
    float4 m3 = ldf4(mmp + 393216 + off), m4 = ldf4(mmp + 524288 + off);
    float4 m5 = ldf4(mmp + 655360 + off), m6 = ldf4(mmp + 786432 + off);
    float4 m7 = ldf4(mmp + 917504 + off);
    v.x = v.x + m1.x + m2.x + m3.x + m4.x + m5.x + m6.x + m7.x;
    v.y = v.y + m1.y + m2.y + m3.y + m4.y + m5.y + m6.y + m7.y;
    v.z = v.z + m1.z + m2.z + m3.z + m4.z + m5.z + m6.z + m7.z;
    v.w = v.w + m1.w + m2.w + m3.w + m4.w + m5.w + m6.w + m7.w;
    float4 me = ldf4(cp + (size_t)(m0 + r) * 2816 + 2304 + i);
    float4 bv4 = ldf4(bvv + i);
    float4 res = {(v.x + bv4.x) * (me.x + 1.0f), (v.y + bv4.y) * (me.y + 1.0f),
                  (v.z + bv4.z) * (me.z + 1.0f), (v.w + bv4.w) * (me.w + 1.0f)};
    ((float4*)AL)[t] = res;
  }
  __syncthreads();
  int kl = t & 63, wid = t >> 6, rg = wid & 1, kh = wid >> 1;
  int col = dc * 256 + 4 * kl;
  float4 acc[8] = {};
  gcore8<32, DD>(AL + (rg * 8) * 64 + kh * 32, 64,
                 We + (size_t)(k0 + kh * 32) * DD + col, acc);
  kred(acc, AL, wid, kl);
  if (!kh) {
    float* dst = op + (size_t)ks * (256 * DD);
#pragma unroll
    for (int j = 0; j < 8; j++)
      *(float4*)(dst + (size_t)(m0 + rg * 8 + j) * DD + col) = acc[j];
  }
}

// ===== Stage 8: epilogue (256 blocks, float4) ==============================
__global__ __launch_bounds__(256, 2) void k_s8(
    const float* __restrict__ op, const float* __restrict__ be,
    const float* __restrict__ gamma, const float* __restrict__ rs,
    float* __restrict__ outp) {
  int m = blockIdx.x, t = threadIdx.x;
  if (t < 192) {
    int d = 4 * t;
    size_t off = (size_t)m * DD + d;
    float4 v = ldf4(op + off);
    float4 o1 = ldf4(op + 196608 + off), o2 = ldf4(op + 393216 + off);
    float4 o3 = ldf4(op + 589824 + off), o4 = ldf4(op + 786432 + off);
    float4 o5 = ldf4(op + 983040 + off), o6 = ldf4(op + 1179648 + off);
    float4 o7 = ldf4(op + 1376256 + off);
    v.x = v.x + o1.x + o2.x + o3.x + o4.x + o5.x + o6.x + o7.x;
    v.y = v.y + o1.y + o2.y + o3.y + o4.y + o5.y + o6.y + o7.y;
    v.z = v.z + o1.z + o2.z + o3.z + o4.z + o5.z + o6.z + o7.z;
    v.w = v.w + o1.w + o2.w + o3.w + o4.w + o5.w + o6.w + o7.w;
    float4 bev = ldf4(be + d), gv = ldf4(gamma + d);
    float4 rv = ldf4(rs + off);
    float4 out = {rv.x + (v.x + bev.x) * gv.x, rv.y + (v.y + bev.y) * gv.y,
                  rv.z + (v.z + bev.z) * gv.z, rv.w + (v.w + bev.w) * gv.w};
    *(float4*)(outp + off) = out;
  }
}

extern "C" void kernel_launch(void* const* d_in, const int* in_sizes, int n_in,
                              void* d_out, int out_size, void* d_ws, size_t ws_size,
                              hipStream_t stream) {
  const float* rs     = (const float*)d_in[0];
  const float* codes  = (const float*)d_in[1];
  const float* ss     = (const float*)d_in[2];
  const float* ln_r_g = (const float*)d_in[3];
  const float* ln_r_b = (const float*)d_in[4];
  const float* ln_s_g = (const float*)d_in[5];
  const float* ln_s_b = (const float*)d_in[6];
  const float* Wq  = (const float*)d_in[7];
  const float* bq  = (const float*)d_in[8];
  const float* Wk  = (const float*)d_in[10];
  const float* bk  = (const float*)d_in[11];
  const float* Wmq = (const float*)d_in[9];
  const float* Wmk = (const float*)d_in[12];
  const float* Wv  = (const float*)d_in[13];
  const float* bv  = (const float*)d_in[14];
  const float* Wmv = (const float*)d_in[15];
  const float* We  = (const float*)d_in[16];
  const float* be  = (const float*)d_in[17];
  const float* Wme = (const float*)d_in[18];
  const float* gamma = (const float*)d_in[19];

  float* w = (float*)d_ws;
  // liveness-aliased layout (float offsets); peak ≈ 28.3 MB
  float* s_ln = w;                  // @0        786432  (s1 -> s5)
  float* r_ln = w + 786432;         //           196608  (s1 -> s2)
  float* WkT  = w + 983040;         //           393216  (s1 -> s3)
  float* qp   = w + 1376256;        //           524288  (s2 -> s3, 4 partials)
  float* sT   = w + 1900544;        //           786432  (s2 -> s4)
  float* cp   = w + 2686976;        //           720896  (s1 -> s7) [m][2816]
  float* qbk  = w + 3407872;        //             2048  (s3 -> s5)
  float* qm   = w + 3409920;        //          1572864  (s3 -> s4)
  float* scp  = w + 4982784;        //          2097152  (s4 -> s5, 4 partials)
  float* wsm  = qm;                 // alias (s5 -> s6)
  float* mmp  = r_ln;               // alias r_ln+WkT+qp region (s6 -> s7, 8 partials)
  float* op   = scp;                // alias (s7 -> s8, 8 partials)

  k_s1<<<dim3(592), 256, 0, stream>>>(ss, rs, ln_s_g, ln_s_b, ln_r_g, ln_r_b,
                                      codes, Wmq, Wmk, Wmv, Wme, Wk,
                                      s_ln, r_ln, cp, WkT);
  k_s2<<<dim3(320), 256, 0, stream>>>(s_ln, r_ln, cp, Wq, sT, qp);
  k_s3<<<dim3(384), 256, 0, stream>>>(qp, bq, WkT, cp, bk, qm, qbk);
  k_s4<<<dim3(512), 256, 0, stream>>>(qm, sT, scp);
  k_s5<<<dim3(384), 256, 0, stream>>>(scp, qbk, s_ln, cp, wsm);
  k_s6<<<dim3(256), 256, 0, stream>>>(wsm, Wv, mmp);
  k_s7<<<dim3(384), 256, 0, stream>>>(mmp, bv, cp, We, op);
  k_s8<<<dim3(256), 256, 0, stream>>>(op, be, gamma, rs, (float*)d_out);
}

// Round 11
// 179.587 us; speedup vs baseline: 3.0255x; 1.0197x over previous
//
#include <hip/hip_runtime.h>

// ReadInAttention — v10: 7-stage pipeline (s3 fused into s4).
// v9 minus the qm round-trip: s4 blocks regrouped to 16 m x 1 head with
// score K-split 3x256, so each block computes its own qm slice in-LDS
// (s3's exact staging + gcore8<32,DD> + mk modulation), then the score
// partial gcore8<128,VV>. qbk fold rides along under ks==0.
// All stages __launch_bounds__(256,2) (4-wave min spills: v7/v8).

#define DD 768
#define CDIM 384
#define NH 8
#define HD 64
#define INNER 512
#define VV 256

__device__ __forceinline__ float4 ldf4(const float* p) {
  return *(const float4*)(p);
}

__device__ __forceinline__ void fma4(float4& a, float s, const float4& b) {
  a.x += s * b.x; a.y += s * b.y; a.z += s * b.z; a.w += s * b.w;
}

// 8 rows x 8 k FMA block. A fragments as float4 pairs (2 rows at a time).
__device__ __forceinline__ void fma_chunk8(const float* __restrict__ Aw,
                                           int lda, int kk, const float4* b,
                                           float4* acc) {
#pragma unroll
  for (int rg = 0; rg < 4; rg++) {
    const float* ap = Aw + (rg * 2) * lda + kk;
    float4 a0l = ldf4(ap);
    float4 a0h = ldf4(ap + 4);
    float4 a1l = ldf4(ap + lda);
    float4 a1h = ldf4(ap + lda + 4);
    float4* ac = acc + rg * 2;
    fma4(ac[0], a0l.x, b[0]); fma4(ac[1], a1l.x, b[0]);
    fma4(ac[0], a0l.y, b[1]); fma4(ac[1], a1l.y, b[1]);
    fma4(ac[0], a0l.z, b[2]); fma4(ac[1], a1l.z, b[2]);
    fma4(ac[0], a0l.w, b[3]); fma4(ac[1], a1l.w, b[3]);
    fma4(ac[0], a0h.x, b[4]); fma4(ac[1], a1h.x, b[4]);
    fma4(ac[0], a0h.y, b[5]); fma4(ac[1], a1h.y, b[5]);
    fma4(ac[0], a0h.z, b[6]); fma4(ac[1], a1h.z, b[6]);
    fma4(ac[0], a0h.w, b[7]); fma4(ac[1], a1h.w, b[7]);
  }
}

// Per-wave GEMM over a K-half: 8 rows x (64 lanes * float4) cols.
// KQ = K/2, multiple of 16. Aw/Bp pre-offset to this wave's rows/K-half.
template <int KQ, int NS>
__device__ __forceinline__ void gcore8(const float* __restrict__ Aw, int lda,
                                       const float* __restrict__ Bp,
                                       float4* acc) {
  float4 b0[8], b1[8];
  const float* Bq = Bp;
#pragma unroll
  for (int i = 0; i < 8; i++) b0[i] = ldf4(Bq + (size_t)i * NS);
  Bq += (size_t)8 * NS;
#pragma unroll 1
  for (int kk = 0; kk + 16 <= KQ; kk += 16) {
#pragma unroll
    for (int i = 0; i < 8; i++) b1[i] = ldf4(Bq + (size_t)i * NS);
    Bq += (size_t)8 * NS;
    fma_chunk8(Aw, lda, kk, b0, acc);
    if (kk + 16 < KQ) {
#pragma unroll
      for (int i = 0; i < 8; i++) b0[i] = ldf4(Bq + (size_t)i * NS);
      Bq += (size_t)8 * NS;
    }
    fma_chunk8(Aw, lda, kk + 8, b1, acc);
  }
}

// Cross-K-half reduce via LDS. After: wave 0 holds rows 0-7, wave 1 rows
// 8-15 (kh==0); waves 2,3 done.
__device__ __forceinline__ void kred(float4* acc, float* RED, int wid,
                                     int kl) {
  __syncthreads();
  float4* R4 = (float4*)RED;
  int rg = wid & 1, kh = wid >> 1;
  if (kh) {
#pragma unroll
    for (int r = 0; r < 8; r++) R4[(rg * 8 + r) * 64 + kl] = acc[r];
  }
  __syncthreads();
  if (!kh) {
#pragma unroll
    for (int r = 0; r < 8; r++) {
      float4 v = R4[(rg * 8 + r) * 64 + kl];
      acc[r].x += v.x; acc[r].y += v.y; acc[r].z += v.z; acc[r].w += v.w;
    }
  }
}

// ===== Stage 1: code GEMM [0,176) | WkT [176,272) | LN [272,592) ===========
__global__ __launch_bounds__(256, 2) void k_s1(
    const float* __restrict__ ss, const float* __restrict__ rs,
    const float* __restrict__ g_s, const float* __restrict__ b_s,
    const float* __restrict__ g_r, const float* __restrict__ b_r,
    const float* __restrict__ codes, const float* __restrict__ Wmq,
    const float* __restrict__ Wmk, const float* __restrict__ Wmv,
    const float* __restrict__ Wme, const float* __restrict__ Wk,
    float* __restrict__ s_ln, float* __restrict__ r_ln,
    float* __restrict__ cp, float* __restrict__ WkT) {
  __shared__ __align__(16) float SB[6144];
  int bid = blockIdx.x, t = threadIdx.x;
  if (bid < 176) {  // ---- code GEMM: 16 rows x 256 cols, K=384 (192/half) --
    int nc = bid % 11, mb = bid / 11;
    int base = nc * 256;
    const float* W; int N, colW;
    if (base < 768)       { W = Wmq; N = DD;    colW = base; }
    else if (base < 1536) { W = Wmk; N = DD;    colW = base - 768; }
    else if (base < 2304) { W = Wmv; N = DD;    colW = base - 1536; }
    else                  { W = Wme; N = INNER; colW = base - 2304; }
    int m0 = mb * 16;
#pragma unroll
    for (int p = 0; p < 24; p++) {
      int idx = p * 256 + t, r = idx / 384, k = idx % 384;
      SB[idx] = codes[(size_t)(m0 + r) * CDIM + k];
    }
    __syncthreads();
    int kl = t & 63, wid = t >> 6, rg = wid & 1, kh = wid >> 1;
    float4 acc[8] = {};
    const float* Aw = SB + (rg * 8) * 384 + kh * 192;
    if (N == DD)
      gcore8<192, DD>(Aw, 384, W + (size_t)(kh * 192) * DD + colW + 4 * kl, acc);
    else
      gcore8<192, INNER>(Aw, 384, W + (size_t)(kh * 192) * INNER + colW + 4 * kl, acc);
    kred(acc, SB, wid, kl);
    if (!kh) {
      int gcol = base + 4 * kl;
#pragma unroll
      for (int j = 0; j < 8; j++)
        *(float4*)(cp + (size_t)(m0 + rg * 8 + j) * 2816 + gcol) = acc[j];
    }
  } else if (bid < 272) {  // ---- Wk transpose ----
    int tid = bid - 176;
    int d0 = (tid >> 3) * 64, c0 = (tid & 7) * 64;
    int j = t & 63, i0 = t >> 6;
#pragma unroll
    for (int p = 0; p < 16; p++) {
      int i = p * 4 + i0;
      SB[i * 65 + j] = Wk[(size_t)(d0 + i) * INNER + c0 + j];
    }
    __syncthreads();
#pragma unroll
    for (int p = 0; p < 16; p++) {
      int i = p * 4 + i0;
      WkT[(size_t)(c0 + i) * DD + d0 + j] = SB[j * 65 + i];
    }
  } else {  // ---- LayerNorm: 4 rows/block, 1 row/wave, shfl-only reduce ----
    int rr = (bid - 272) * 4 + (t >> 6);  // < 1280
    const float *x, *g, *bb; float* y; int r;
    if (rr < 1024) { x = ss; g = g_s; bb = b_s; y = s_ln; r = rr; }
    else           { x = rs; g = g_r; bb = b_r; y = r_ln; r = rr - 1024; }
    const float* xr = x + (size_t)r * DD;
    int lane = t & 63;
    float v[12];
    float s = 0.f, sq = 0.f;
#pragma unroll
    for (int j = 0; j < 12; j++) {
      v[j] = xr[lane + 64 * j];
      s += v[j]; sq += v[j] * v[j];
    }
    for (int o = 32; o > 0; o >>= 1) {
      s += __shfl_down(s, o, 64); sq += __shfl_down(sq, o, 64);
    }
    s = __shfl(s, 0, 64); sq = __shfl(sq, 0, 64);
    float mu = s * (1.0f / 768.0f);
    float var = sq * (1.0f / 768.0f) - mu * mu;
    float rstd = rsqrtf(var + 1e-5f);
    float* yr = y + (size_t)r * DD;
#pragma unroll
    for (int j = 0; j < 12; j++) {
      int d = lane + 64 * j;
      yr[d] = (v[j] - mu) * rstd * g[d] + bb[d];
    }
  }
}

// ===== Stage 2: q partial [0,128) (Kc=192, 96/half) | sT [128,320) =========
__global__ __launch_bounds__(256, 2) void k_s2(
    const float* __restrict__ s_ln, const float* __restrict__ r_ln,
    const float* __restrict__ cp, const float* __restrict__ Wq,
    float* __restrict__ sT, float* __restrict__ qp) {
  __shared__ __align__(16) float SB[4160];
  int bid = blockIdx.x, t = threadIdx.x;
  if (bid < 128) {
    int ks = bid & 3, tile = bid >> 2, nc = tile & 1, mb = tile >> 1;
    int m0 = mb * 16, col0 = nc * 256, k0 = ks * 192;
#pragma unroll
    for (int p = 0; p < 12; p++) {
      int idx = p * 256 + t, r = idx / 192, k = idx % 192;
      int d = k0 + k;
      float mqv = cp[(size_t)(m0 + r) * 2816 + d] + 1.0f;
      SB[idx] = r_ln[(size_t)(m0 + r) * DD + d] * mqv;
    }
    __syncthreads();
    int kl = t & 63, wid = t >> 6, rg = wid & 1, kh = wid >> 1;
    int col = col0 + 4 * kl;
    float4 acc[8] = {};
    gcore8<96, INNER>(SB + (rg * 8) * 192 + kh * 96, 192,
                      Wq + (size_t)(k0 + kh * 96) * INNER + col, acc);
    kred(acc, SB, wid, kl);
    if (!kh) {
      float* dst = qp + (size_t)ks * (256 * INNER);
#pragma unroll
      for (int j = 0; j < 8; j++)
        *(float4*)(dst + (size_t)(m0 + rg * 8 + j) * INNER + col) = acc[j];
    }
  } else {  // ---- sT[b][d][v] ----
    int tid = bid - 128;
    int vt = tid & 3, dt = (tid >> 2) % 12, b = tid / 48;
    int v0 = vt * 64, d0 = dt * 64;
    int j = t & 63, i0 = t >> 6;
#pragma unroll
    for (int p = 0; p < 16; p++) {
      int i = p * 4 + i0;
      SB[i * 65 + j] = s_ln[(size_t)(b * VV + v0 + i) * DD + d0 + j];
    }
    __syncthreads();
#pragma unroll
    for (int p = 0; p < 16; p++) {
      int i = p * 4 + i0;
      sT[((size_t)b * DD + d0 + i) * VV + v0 + j] = SB[j * 65 + i];
    }
  }
}

// ===== Stage 3+4 fused: qmk slice + scores partial (384 blocks) ============
// bid = ks*128 + h*16 + mb; ks in [0,3) (Kc=256), h in [0,8), mb in [0,16).
// Rows: 16 m of one head. Phase 1: qm slice in LDS; phase 2: score partial.
__global__ __launch_bounds__(256, 2) void k_s34(
    const float* __restrict__ qp, const float* __restrict__ bq,
    const float* __restrict__ WkT, const float* __restrict__ cp,
    const float* __restrict__ bk, const float* __restrict__ sT,
    float* __restrict__ scp, float* __restrict__ qbk) {
  __shared__ __align__(16) float SB[4096];
  int bid = blockIdx.x, t = threadIdx.x;
  int mb = bid & 15, h = (bid >> 4) & 7, ks = bid >> 7;
  int m0 = mb * 16, b = mb >> 2, k0 = ks * 256;
  {  // stage q_h[16][64]: sum 4 qp partials + bq (s3's verified staging)
    int r = t >> 4, c4 = (t & 15) * 4;
    int i = h * HD + c4;
    size_t off = (size_t)(m0 + r) * INNER + i;
    float4 q0 = ldf4(qp + off), q1 = ldf4(qp + 131072 + off);
    float4 q2 = ldf4(qp + 262144 + off), q3 = ldf4(qp + 393216 + off);
    float4 bq4 = ldf4(bq + i);
    float4 s;
    s.x = q0.x + q1.x + q2.x + q3.x + bq4.x;
    s.y = q0.y + q1.y + q2.y + q3.y + bq4.y;
    s.z = q0.z + q1.z + q2.z + q3.z + bq4.z;
    s.w = q0.w + q1.w + q2.w + q3.w + bq4.w;
    ((float4*)SB)[t] = s;
  }
  __syncthreads();
  if (ks == 0) {  // ---- folded qbk (v9-verified): partial per 4-col group
    int m = t >> 4, cg = t & 15;
    const float* bkh = bk + h * HD;
    float p = 0.f;
#pragma unroll
    for (int c = 4 * cg; c < 4 * cg + 4; c++) p += SB[m * HD + c] * bkh[c];
    SB[1024 + t] = p;
  }
  __syncthreads();
  if (ks == 0 && t < 16) {
    float a = 0.f;
#pragma unroll
    for (int i = 0; i < 16; i++) a += SB[1024 + t * 16 + i];
    qbk[(m0 + t) * NH + h] = a;
  }
  int kl = t & 63, wid = t >> 6, rg = wid & 1, kh = wid >> 1;
  // ---- phase 1: qm slice [16][256] = q_h @ WkT[h-slice][k0..k0+256) ----
  float4 acc[8] = {};
  gcore8<32, DD>(SB + (rg * 8) * HD + kh * 32, HD,
                 WkT + (size_t)(h * HD + kh * 32) * DD + k0 + 4 * kl, acc);
  kred(acc, SB, wid, kl);
  __syncthreads();  // kred reads done before qmS overwrites scratch
  if (!kh) {
#pragma unroll
    for (int j = 0; j < 8; j++) {
      int m = m0 + rg * 8 + j;
      const float* mkp = cp + (size_t)m * 2816 + 768 + k0 + 4 * kl;
      float4 o = {acc[j].x * (mkp[0] + 1.0f), acc[j].y * (mkp[1] + 1.0f),
                  acc[j].z * (mkp[2] + 1.0f), acc[j].w * (mkp[3] + 1.0f)};
      *(float4*)(SB + (rg * 8 + j) * 256 + 4 * kl) = o;
    }
  }
  __syncthreads();
  // ---- phase 2: score partial [16][256] = qmS @ sT[b][k0..k0+256)[*] ----
  float4 acc2[8] = {};
  gcore8<128, VV>(SB + (rg * 8) * 256 + kh * 128, 256,
                  sT + ((size_t)b * DD + k0 + kh * 128) * VV + 4 * kl, acc2);
  kred(acc2, SB, wid, kl);
  if (!kh) {
    float* dst = scp + (size_t)ks * (2048 * VV);
#pragma unroll
    for (int j = 0; j < 8; j++) {
      int gi = (m0 + rg * 8 + j) * NH + h;
      *(float4*)(dst + (size_t)gi * VV + 4 * kl) = acc2[j];
    }
  }
}

// ===== Stage 5: softmax + ws GEMM (384 blocks, K=256, 128/half) ============
__global__ __launch_bounds__(256, 2) void k_s5(
    const float* __restrict__ scp, const float* __restrict__ qbk,
    const float* __restrict__ s_ln, const float* __restrict__ cp,
    float* __restrict__ wsm) {
  __shared__ __align__(16) float SC[4096];
  int bid = blockIdx.x, t = threadIdx.x;
  int dc = bid % 3, up = (bid / 3) % 32, b = bid / 96;
  int gi0 = b * 512 + up * 16;
  float4* SC4 = (float4*)SC;
#pragma unroll
  for (int p = 0; p < 4; p++) {
    int idx4 = p * 256 + t;
    int r = idx4 >> 6, c4 = (idx4 & 63) * 4;
    size_t o = (size_t)(gi0 + r) * VV + c4;
    float4 v0 = ldf4(scp + o), v1 = ldf4(scp + 524288 + o);
    float4 v2 = ldf4(scp + 1048576 + o);
    int m = b * 64 + up * 2 + (r >> 3), h = r & 7;
    float qb = qbk[m * NH + h];
    float4 s;
    s.x = (v0.x + v1.x + v2.x + qb) * 0.125f;
    s.y = (v0.y + v1.y + v2.y + qb) * 0.125f;
    s.z = (v0.z + v1.z + v2.z + qb) * 0.125f;
    s.w = (v0.w + v1.w + v2.w + qb) * 0.125f;
    SC4[idx4] = s;
  }
  __syncthreads();
  int wid = t >> 6, lane = t & 63;
#pragma unroll
  for (int j = 0; j < 4; j++) {
    int r = wid * 4 + j;
    float x0 = SC[r * 256 + lane],       x1 = SC[r * 256 + lane + 64];
    float x2 = SC[r * 256 + lane + 128], x3 = SC[r * 256 + lane + 192];
    float mx = fmaxf(fmaxf(x0, x1), fmaxf(x2, x3));
    for (int o = 1; o < 64; o <<= 1) mx = fmaxf(mx, __shfl_xor(mx, o, 64));
    float e0 = __expf(x0 - mx), e1 = __expf(x1 - mx);
    float e2 = __expf(x2 - mx), e3 = __expf(x3 - mx);
    float sm = e0 + e1 + e2 + e3;
    for (int o = 1; o < 64; o <<= 1) sm += __shfl_xor(sm, o, 64);
    float rinv = 1.0f / sm;
    SC[r * 256 + lane] = e0 * rinv;       SC[r * 256 + lane + 64] = e1 * rinv;
    SC[r * 256 + lane + 128] = e2 * rinv; SC[r * 256 + lane + 192] = e3 * rinv;
  }
  __syncthreads();
  int kl = t & 63, rg = wid & 1, kh = wid >> 1;
  int col = dc * 256 + 4 * kl;
  float4 acc[8] = {};
  gcore8<128, DD>(SC + (rg * 8) * 256 + kh * 128, 256,
                  s_ln + (size_t)(b * VV + kh * 128) * DD + col, acc);
  kred(acc, SC, wid, kl);
  if (!kh) {
#pragma unroll
    for (int j = 0; j < 8; j++) {
      // row r = rg*8+j -> head j, u-slot rg
      int m = b * 64 + up * 2 + rg;
      const float* mvp = cp + (size_t)m * 2816 + 1536 + col;
      float4 o = {acc[j].x * (mvp[0] + 1.0f), acc[j].y * (mvp[1] + 1.0f),
                  acc[j].z * (mvp[2] + 1.0f), acc[j].w * (mvp[3] + 1.0f)};
      *(float4*)(wsm + ((size_t)j * 256 + m) * DD + col) = o;
    }
  }
}

// ===== Stage 6: msg partial (256 blocks, Kc=96, 48/half) ===================
__global__ __launch_bounds__(256, 2) void k_s6(
    const float* __restrict__ wsm, const float* __restrict__ Wv,
    float* __restrict__ mmp) {
  __shared__ __align__(16) float AL[6144];
  int bid = blockIdx.x, t = threadIdx.x;
  int hp = bid & 1, ks = (bid >> 1) & 7, mb = bid >> 4;
  int h0 = hp * 4, m0 = mb * 16, k0 = ks * 96;
#pragma unroll
  for (int p = 0; p < 24; p++) {
    int idx = p * 256 + t;
    int e = idx / 1536, rem = idx % 1536, r = rem / 96, k = rem % 96;
    AL[idx] = wsm[((size_t)(h0 + e) * 256 + m0 + r) * DD + k0 + k];
  }
  __syncthreads();
  int kl = t & 63, wid = t >> 6, rg = wid & 1, kh = wid >> 1;
  int hs = kl >> 4, c4 = 4 * (kl & 15);
  int colg = h0 * HD + hs * HD + c4;
  const float* Aw = AL + hs * 1536 + (rg * 8) * 96 + kh * 48;
  float4 acc[8] = {};
  gcore8<48, INNER>(Aw, 96, Wv + (size_t)(k0 + kh * 48) * INNER + colg, acc);
  kred(acc, AL, wid, kl);
  if (!kh) {
    float* dst = mmp + (size_t)ks * (256 * INNER);
#pragma unroll
    for (int j = 0; j < 8; j++)
      *(float4*)(dst + (size_t)(m0 + rg * 8 + j) * INNER + colg) = acc[j];
  }
}

// ===== Stage 7: out partial (384 blocks, Kc=64, 32/half) ===================
__global__ __launch_bounds__(256, 2) void k_s7(
    const float* __restrict__ mmp, const float* __restrict__ bvv,
    const float* __restrict__ cp, const float* __restrict__ We,
    float* __restrict__ op) {
  __shared__ __align__(16) float AL[4096];
  int bid = blockIdx.x, t = threadIdx.x;
  int ks = bid & 7, dc = (bid >> 3) % 3, mb = bid / 24;
  int m0 = mb * 16, k0 = ks * 64;
  {  // staging: 1024 floats = 256 float4, one per thread
    int r = t >> 4, k4 = (t & 15) * 4;
    int i = k0 + k4;
    size_t off = (size_t)(m0 + r) * INNER + i;
    float4 v = ldf4(mmp + off);
    float4 m1 = ldf4(mmp + 131072 + off), m2 = ldf4(mmp + 262144 + off);
    float4 m3 = ldf4(mmp + 393216 + off), m4 = ldf4(mmp + 524288 + off);
    float4 m5 = ldf4(mmp + 655360 + off), m6 = ldf4(mmp + 786432 + off);
    float4 m7 = ldf4(mmp + 917504 + off);
    v.x = v.x + m1.x + m2.x + m3.x + m4.x + m5.x + m6.x + m7.x;
    v.y = v.y + m1.y + m2.y + m3.y + m4.y + m5.y + m6.y + m7.y;
    v.z = v.z + m1.z + m2.z + m3.z + m4.z + m5.z + m6.z + m7.z;
    v.w = v.w + m1.w + m2.w + m3.w + m4.w + m5.w + m6.w + m7.w;
    float4 me = ldf4(cp + (size_t)(m0 + r) * 2816 + 2304 + i);
    float4 bv4 = ldf4(bvv + i);
    float4 res = {(v.x + bv4.x) * (me.x + 1.0f), (v.y + bv4.y) * (me.y + 1.0f),
                  (v.z + bv4.z) * (me.z + 1.0f), (v.w + bv4.w) * (me.w + 1.0f)};
    ((float4*)AL)[t] = res;
  }
  __syncthreads();
  int kl = t & 63, wid = t >> 6, rg = wid & 1, kh = wid >> 1;
  int col = dc * 256 + 4 * kl;
  float4 acc[8] = {};
  gcore8<32, DD>(AL + (rg * 8) * 64 + kh * 32, 64,
                 We + (size_t)(k0 + kh * 32) * DD + col, acc);
  kred(acc, AL, wid, kl);
  if (!kh) {
    float* dst = op + (size_t)ks * (256 * DD);
#pragma unroll
    for (int j = 0; j < 8; j++)
      *(float4*)(dst + (size_t)(m0 + rg * 8 + j) * DD + col) = acc[j];
  }
}

// ===== Stage 8: epilogue (256 blocks, float4) ==============================
__global__ __launch_bounds__(256, 2) void k_s8(
    const float* __restrict__ op, const float* __restrict__ be,
    const float* __restrict__ gamma, const float* __restrict__ rs,
    float* __restrict__ outp) {
  int m = blockIdx.x, t = threadIdx.x;
  if (t < 192) {
    int d = 4 * t;
    size_t off = (size_t)m * DD + d;
    float4 v = ldf4(op + off);
    float4 o1 = ldf4(op + 196608 + off), o2 = ldf4(op + 393216 + off);
    float4 o3 = ldf4(op + 589824 + off), o4 = ldf4(op + 786432 + off);
    float4 o5 = ldf4(op + 983040 + off), o6 = ldf4(op + 1179648 + off);
    float4 o7 = ldf4(op + 1376256 + off);
    v.x = v.x + o1.x + o2.x + o3.x + o4.x + o5.x + o6.x + o7.x;
    v.y = v.y + o1.y + o2.y + o3.y + o4.y + o5.y + o6.y + o7.y;
    v.z = v.z + o1.z + o2.z + o3.z + o4.z + o5.z + o6.z + o7.z;
    v.w = v.w + o1.w + o2.w + o3.w + o4.w + o5.w + o6.w + o7.w;
    float4 bev = ldf4(be + d), gv = ldf4(gamma + d);
    float4 rv = ldf4(rs + off);
    float4 out = {rv.x + (v.x + bev.x) * gv.x, rv.y + (v.y + bev.y) * gv.y,
                  rv.z + (v.z + bev.z) * gv.z, rv.w + (v.w + bev.w) * gv.w};
    *(float4*)(outp + off) = out;
  }
}

extern "C" void kernel_launch(void* const* d_in, const int* in_sizes, int n_in,
                              void* d_out, int out_size, void* d_ws, size_t ws_size,
                              hipStream_t stream) {
  const float* rs     = (const float*)d_in[0];
  const float* codes  = (const float*)d_in[1];
  const float* ss     = (const float*)d_in[2];
  const float* ln_r_g = (const float*)d_in[3];
  const float* ln_r_b = (const float*)d_in[4];
  const float* ln_s_g = (const float*)d_in[5];
  const float* ln_s_b = (const float*)d_in[6];
  const float* Wq  = (const float*)d_in[7];
  const float* bq  = (const float*)d_in[8];
  const float* Wk  = (const float*)d_in[10];
  const float* bk  = (const float*)d_in[11];
  const float* Wmq = (const float*)d_in[9];
  const float* Wmk = (const float*)d_in[12];
  const float* Wv  = (const float*)d_in[13];
  const float* bv  = (const float*)d_in[14];
  const float* Wmv = (const float*)d_in[15];
  const float* We  = (const float*)d_in[16];
  const float* be  = (const float*)d_in[17];
  const float* Wme = (const float*)d_in[18];
  const float* gamma = (const float*)d_in[19];

  float* w = (float*)d_ws;
  // liveness-aliased layout (float offsets); peak ≈ 28.3 MB
  float* s_ln = w;                  // @0        786432  (s1 -> s5)
  float* r_ln = w + 786432;         //           196608  (s1 -> s2)
  float* WkT  = w + 983040;         //           393216  (s1 -> s34)
  float* qp   = w + 1376256;        //           524288  (s2 -> s34, 4 partials)
  float* sT   = w + 1900544;        //           786432  (s2 -> s34)
  float* cp   = w + 2686976;        //           720896  (s1 -> s7) [m][2816]
  float* qbk  = w + 3407872;        //             2048  (s34 -> s5)
  float* qm   = w + 3409920;        //          1572864  (now only wsm alias)
  float* scp  = w + 4982784;        //          1572864  (s34 -> s5, 3 partials)
  float* wsm  = qm;                 // (s5 -> s6)
  float* mmp  = r_ln;               // alias r_ln+WkT+qp region (s6 -> s7, 8 partials)
  float* op   = scp;                // alias (s7 -> s8, 8 partials)

  k_s1<<<dim3(592), 256, 0, stream>>>(ss, rs, ln_s_g, ln_s_b, ln_r_g, ln_r_b,
                                      codes, Wmq, Wmk, Wmv, Wme, Wk,
                                      s_ln, r_ln, cp, WkT);
  k_s2<<<dim3(320), 256, 0, stream>>>(s_ln, r_ln, cp, Wq, sT, qp);
  k_s34<<<dim3(384), 256, 0, stream>>>(qp, bq, WkT, cp, bk, sT, scp, qbk);
  k_s5<<<dim3(384), 256, 0, stream>>>(scp, qbk, s_ln, cp, wsm);
  k_s6<<<dim3(256), 256, 0, stream>>>(wsm, Wv, mmp);
  k_s7<<<dim3(384), 256, 0, stream>>>(mmp, bv, cp, We, op);
  k_s8<<<dim3(256), 256, 0, stream>>>(op, be, gamma, rs, (float*)d_out);
}